// Round 3
// baseline (2584.040 us; speedup 1.0000x reference)
//
#include <hip/hip_runtime.h>
#include <stdint.h>

#define S   128
#define NB  32
#define NC  256
#define DK  128

typedef __bf16 bf16x8 __attribute__((ext_vector_type(8)));
typedef float  f32x16 __attribute__((ext_vector_type(16)));
typedef unsigned int u32x4 __attribute__((ext_vector_type(4)));
static_assert(sizeof(bf16x8) == 16, "bf16x8 size");
static_assert(sizeof(u32x4) == 16, "u32x4 size");

// d_ws layout (float offsets). HT reuses AL region (AL consumed by k1 before kmain writes HT).
#define OFF_AL   0
#define OFF_HT   OFF_AL
#define OFF_P2   524288
#define OFF_P3   1044480
#define OFF_PS   1564672
#define OFF_PY   2084864
#define OFF_WT5  2654208

__device__ __forceinline__ float v_exp2(float x){ float r; asm("v_exp_f32 %0, %1" : "=v"(r) : "v"(x)); return r; }
__device__ __forceinline__ float v_rcp (float x){ float r; asm("v_rcp_f32 %0, %1" : "=v"(r) : "v"(x)); return r; }
__device__ __forceinline__ float sigm(float x){ return v_rcp(1.0f + v_exp2(x * -1.4426950408889634f)); }
__device__ __forceinline__ uint32_t pkbf(float lo, float hi){
  uint32_t r; asm("v_cvt_pk_bf16_f32 %0, %1, %2" : "=v"(r) : "v"(lo), "v"(hi)); return r;
}
#define NLOG2E (-1.4426950408889634f)

// ---------------- kernel 0: AL = concat(e_emb, at_emb, a*ones50) @ W1 + b1 ----------------
__global__ __launch_bounds__(512) void k0_al(
    const int* __restrict__ e_data, const int* __restrict__ at_data,
    const float* __restrict__ a_data, const float* __restrict__ e_E,
    const float* __restrict__ at_E, const float* __restrict__ W1,
    const float* __restrict__ b1, float* __restrict__ ws)
{
  __shared__ float ein[32][128];
  __shared__ float atin[32][128];
  int b = blockIdx.x >> 2, q4 = blockIdx.x & 3, t0 = q4 * 32;
  for (int idx = threadIdx.x; idx < 32 * 128; idx += 512) {
    int r = idx >> 7, j = idx & 127;
    int ev  = e_data [b * S + t0 + r];
    int atv = at_data[b * S + t0 + r];
    ein [r][j] = e_E [ev  * DK + j];
    atin[r][j] = at_E[atv * DK + j];
  }
  __syncthreads();
  int j = threadIdx.x & 127, tq = threadIdx.x >> 7;
  float w1s = 0.f;
  for (int d = 0; d < 50; ++d) w1s += W1[(256 + d) * DK + j];
  float acc[8];
#pragma unroll
  for (int u = 0; u < 8; ++u) {
    int t = t0 + tq * 8 + u;
    acc[u] = b1[j] + a_data[b * S + t] * w1s;
  }
  for (int k = 0; k < 128; ++k) {
    float w = W1[k * DK + j];
#pragma unroll
    for (int u = 0; u < 8; ++u) acc[u] += ein[tq * 8 + u][k] * w;
  }
  for (int k = 0; k < 128; ++k) {
    float w = W1[(128 + k) * DK + j];
#pragma unroll
    for (int u = 0; u < 8; ++u) acc[u] += atin[tq * 8 + u][k] * w;
  }
#pragma unroll
  for (int u = 0; u < 8; ++u)
    ws[OFF_AL + (b * S + t0 + tq * 8 + u) * DK + j] = acc[u];
}

// ---------------- kernel T: transpose W5 h-block into ws (for k2_y row-dots) ----------------
__global__ __launch_bounds__(256) void kT_tr(const float* __restrict__ W5, float* __restrict__ ws)
{
  int idx = blockIdx.x * 256 + threadIdx.x;   // 0..16383
  int j = idx >> 7, k = idx & 127;
  ws[OFF_WT5 + j * DK + k] = W5[(128 + k) * DK + j];
}

// ---------------- kernel 1: carry-independent per-step preactivations ----------------
__global__ __launch_bounds__(512) void k1_pre(
    const int* __restrict__ e_data, const int* __restrict__ it_data,
    const float* __restrict__ it_E, const float* __restrict__ e_E,
    const float* __restrict__ W2, const float* __restrict__ b2,
    const float* __restrict__ W3, const float* __restrict__ b3,
    const float* __restrict__ W4, const float* __restrict__ b4,
    const float* __restrict__ W5, const float* __restrict__ b5,
    float* __restrict__ ws)
{
  __shared__ float als[33][128];
  __shared__ float its[32][128];
  __shared__ float ens[32][128];
  int b = blockIdx.x >> 2, sh = blockIdx.x & 3, s0 = sh * 32;
  for (int idx = threadIdx.x; idx < 33 * 128; idx += 512) {
    int r = idx >> 7, j = idx & 127;
    int srow = s0 - 1 + r;
    als[r][j] = (srow >= 0) ? ws[OFF_AL + (b * S + srow) * DK + j] : 0.f;
  }
  for (int idx = threadIdx.x; idx < 32 * 128; idx += 512) {
    int r = idx >> 7, j = idx & 127;
    int itv = it_data[b * S + s0 + r];
    its[r][j] = it_E[itv * DK + j];
    int sg = s0 + r + 1; if (sg > 127) sg = 127;
    int ev = e_data[b * S + sg];
    ens[r][j] = e_E[ev * DK + j];
  }
  __syncthreads();
  int j = threadIdx.x & 127, sq = threadIdx.x >> 7;
  float p2[8], p3[8], pS[8], pY[8];
#pragma unroll
  for (int u = 0; u < 8; ++u) { p2[u] = b2[j]; p3[u] = b3[j]; pS[u] = b4[j]; pY[u] = b5[j]; }
  for (int k = 0; k < 128; ++k) {
    float w2 = W2[k * DK + j], w3 = W3[k * DK + j];
#pragma unroll
    for (int u = 0; u < 8; ++u) { float v = als[sq * 8 + u][k]; p2[u] += v * w2; p3[u] += v * w3; }
  }
  for (int k = 0; k < 128; ++k) {
    float w2 = W2[(128 + k) * DK + j], w3 = W3[(128 + k) * DK + j], w4 = W4[(256 + k) * DK + j];
#pragma unroll
    for (int u = 0; u < 8; ++u) { float v = its[sq * 8 + u][k]; p2[u] += v * w2; p3[u] += v * w3; pS[u] += v * w4; }
  }
  for (int k = 0; k < 128; ++k) {
    float w2 = W2[(256 + k) * DK + j], w3 = W3[(256 + k) * DK + j];
#pragma unroll
    for (int u = 0; u < 8; ++u) { float v = als[sq * 8 + u + 1][k]; p2[u] += v * w2; p3[u] += v * w3; }
  }
  for (int k = 0; k < 128; ++k) {
    float w5 = W5[k * DK + j];
#pragma unroll
    for (int u = 0; u < 8; ++u) pY[u] += ens[sq * 8 + u][k] * w5;
  }
#pragma unroll
  for (int u = 0; u < 8; ++u) {
    int s = s0 + sq * 8 + u;
    if (s < 127) {
      int o = (b * 127 + s) * DK + j;
      ws[OFF_P2 + o] = p2[u]; ws[OFF_P3 + o] = p3[u];
      ws[OFF_PS + o] = pS[u]; ws[OFF_PY + o] = pY[u];
    }
  }
}

// ---------------- main recurrent kernel ----------------
// 1 block/batch row. Per step 5 phases: A (stageA partial dots, all threads, coalesced),
// A2 (LG finish, 128 thr), B (sbc partials, all thr), X (MFMA + fused gamma/h-update/pack
// + next-step load issue), R (h_tilde reduce + LDS commits of prefetched values).
// wave (cg,jg): cg 0..3 c-band, jg 0..1 j-half. hm f32 master in regs (64),
// bfr = W4h B-frags in regs (64), acc 32 live (ci processed serially).
__global__ __launch_bounds__(512, 2) void kmain(
    const int* __restrict__ e_data, const float* __restrict__ qmat,
    const float* __restrict__ W2, const float* __restrict__ W3,
    const float* __restrict__ W4, const float* __restrict__ h0,
    float* __restrict__ ws, float* __restrict__ out)
{
  __shared__ char  hsb[2][65536];      // h bf16 [c][k], XOR-swizzled, double-buffered
  __shared__ float qbuf[3][256];
  __shared__ float htld[128];
  __shared__ float LGs[128];
  __shared__ float ap[4][128];         // stageA partials [m*2+kh][j]
  __shared__ float sbcp[4][128];       // stageB partials [kq][j] (kq0 includes rS)
  __shared__ float rsd[3][128];        // r2, r3, rS for current step
  __shared__ float htp[4][128];

  const int b = blockIdx.x;
  const int tid = threadIdx.x;
  const int lane = tid & 63, wv = tid >> 6;
  const int cg = wv >> 1, jg = wv & 1;
  const int lo = lane & 31, hi = lane >> 5;

  // B fragments of W4h (rows 0..127): bfr[ji][kk]
  u32x4 bfr[2][8];
#pragma unroll
  for (int ji = 0; ji < 2; ++ji) {
    int jc = jg * 64 + ji * 32 + lo;
#pragma unroll
    for (int kk = 0; kk < 8; ++kk) {
      float w[8];
#pragma unroll
      for (int e = 0; e < 8; ++e) w[e] = W4[(kk * 16 + hi * 8 + e) * DK + jc];
      u32x4 d;
      d[0] = pkbf(w[0], w[1]); d[1] = pkbf(w[2], w[3]);
      d[2] = pkbf(w[4], w[5]); d[3] = pkbf(w[6], w[7]);
      bfr[ji][kk] = d;
    }
  }

  // h0 -> master registers
  float hm[2][2][16];
#pragma unroll
  for (int ci = 0; ci < 2; ++ci)
#pragma unroll
    for (int ji = 0; ji < 2; ++ji)
#pragma unroll
      for (int r = 0; r < 16; ++r) {
        int row = (r & 3) + 8 * (r >> 2) + 4 * hi;
        hm[ci][ji][r] = h0[(cg * 64 + ci * 32 + row) * DK + jg * 64 + ji * 32 + lo];
      }

  // prologue loads
  float qv0 = 0.f, qv1 = 0.f, rv = 0.f;
  if (tid < 256) {
    qv0 = qmat[e_data[b * S] * NC + tid];
    qv1 = qmat[e_data[b * S + 1] * NC + tid];
  }
  {
    int jj = tid & 127, ro = (b * 127 + 0) * DK + jj;
    if (tid < 128)       rv = ws[OFF_P2 + ro];
    else if (tid < 256)  rv = ws[OFF_P3 + ro];
    else if (tid < 384)  rv = ws[OFF_PS + ro];
  }
  // pack h0 into hsb[0]
#pragma unroll
  for (int ci = 0; ci < 2; ++ci)
#pragma unroll
    for (int ji = 0; ji < 2; ++ji)
#pragma unroll
      for (int r = 0; r < 16; ++r) {
        int row = (r & 3) + 8 * (r >> 2) + 4 * hi;
        int c = cg * 64 + ci * 32 + row;
        int jb = (jg * 64 + ji * 32 + lo) * 2;
        uint16_t v = (uint16_t)pkbf(hm[ci][ji][r], 0.f);
        *(uint16_t*)(&hsb[0][0] + c * 256 + (jb ^ ((c & 15) << 4))) = v;
      }
  if (tid < 256) { qbuf[0][tid] = qv0; qbuf[1][tid] = qv1; }
  if (tid < 384) rsd[tid >> 7][tid & 127] = rv;
  __syncthreads();

  // initial h_tilde_0 partials (q0 . h0)
  {
    float ht0[2] = {0.f, 0.f};
#pragma unroll
    for (int ci = 0; ci < 2; ++ci)
#pragma unroll
      for (int r = 0; r < 16; ++r) {
        int row = (r & 3) + 8 * (r >> 2) + 4 * hi;
        float qv = qbuf[0][cg * 64 + ci * 32 + row];
        ht0[0] += qv * hm[ci][0][r];
        ht0[1] += qv * hm[ci][1][r];
      }
#pragma unroll
    for (int ji = 0; ji < 2; ++ji) {
      float v = ht0[ji] + __shfl_xor(ht0[ji], 32);
      if (hi == 0) htp[cg][jg * 64 + ji * 32 + lo] = v;
    }
  }
  __syncthreads();
  if (tid < 128) htld[tid] = htp[0][tid] + htp[1][tid] + htp[2][tid] + htp[3][tid];
  __syncthreads();

#pragma unroll 1
  for (int s = 0; s < S - 1; ++s) {
    // ---- phase A: stageA partial dots (all 512 threads, coalesced [k][j] loads)
    {
      int m = tid >> 8, kh = (tid >> 7) & 1, jA = tid & 127;
      const float* Wm = m ? W3 : W2;
      float p = 0.f;
#pragma unroll 16
      for (int i = 0; i < 64; ++i)
        p += Wm[(384 + kh * 64 + i) * DK + jA] * htld[kh * 64 + i];
      ap[m * 2 + kh][jA] = p;
    }
    __syncthreads(); // 1
    // ---- phase A2: LG finish (128 threads)
    if (tid < 128) {
      float v2 = rsd[0][tid] + ap[0][tid] + ap[1][tid];
      float v3 = rsd[1][tid] + ap[2][tid] + ap[3][tid];
      LGs[tid] = sigm(v3) * sigm(2.f * v2);   // sigmoid(v3)*(tanh(v2)+1)/2
    }
    __syncthreads(); // 2
    // ---- phase B: sbc partials (all 512 threads, coalesced)
    {
      int kq = tid >> 7, jB = tid & 127;
      float p = (kq == 0) ? rsd[2][jB] : 0.f;
#pragma unroll 8
      for (int i = 0; i < 32; ++i)
        p += W4[(128 + kq * 32 + i) * DK + jB] * LGs[kq * 32 + i];
      sbcp[kq][jB] = p;
    }
    __syncthreads(); // 3

    // ---- phase X: MFMA + fused gamma/h-update/pack + next-step load issue
    float qv = 0.f;
    if (tid < 256) qv = qmat[e_data[b * S + min(s + 2, S - 1)] * NC + tid];
    {
      int jj = tid & 127, ro = (b * 127 + min(s + 1, S - 2)) * DK + jj;
      if (tid < 128)       rv = ws[OFF_P2 + ro];
      else if (tid < 256)  rv = ws[OFF_P3 + ro];
      else if (tid < 384)  rv = ws[OFF_PS + ro];
    }
    const char* hrd = &hsb[s & 1][0];
    char*       hwr = &hsb[(s + 1) & 1][0];
    const float* qc = qbuf[s % 3];
    const float* qn = qbuf[(s + 1) % 3];
    int j0 = jg * 64 + lo, j1 = jg * 64 + 32 + lo;
    float sb0 = sbcp[0][j0] + sbcp[1][j0] + sbcp[2][j0] + sbcp[3][j0];
    float sb1 = sbcp[0][j1] + sbcp[1][j1] + sbcp[2][j1] + sbcp[3][j1];
    float sn0 = sb0 * NLOG2E, sn1 = sb1 * NLOG2E;
    float lg0 = LGs[j0], lg1 = LGs[j1];
    float ht[2] = {0.f, 0.f};
#pragma unroll
    for (int ci = 0; ci < 2; ++ci) {
      f32x16 acc0, acc1;
#pragma unroll
      for (int r = 0; r < 16; ++r) { acc0[r] = 0.f; acc1[r] = 0.f; }
      {
        int c = cg * 64 + ci * 32 + lo;
#pragma unroll
        for (int kk = 0; kk < 8; ++kk) {
          bf16x8 af = __builtin_bit_cast(bf16x8,
              *(const u32x4*)(hrd + c * 256 + ((kk * 32 + hi * 16) ^ ((c & 15) << 4))));
          acc0 = __builtin_amdgcn_mfma_f32_32x32x16_bf16(af, __builtin_bit_cast(bf16x8, bfr[0][kk]), acc0, 0, 0, 0);
          acc1 = __builtin_amdgcn_mfma_f32_32x32x16_bf16(af, __builtin_bit_cast(bf16x8, bfr[1][kk]), acc1, 0, 0, 0);
        }
      }
#pragma unroll
      for (int r = 0; r < 16; ++r) {
        int row = (r & 3) + 8 * (r >> 2) + 4 * hi;
        int c = cg * 64 + ci * 32 + row;
        float qe = qc[c], qq = qn[c];
        float g0 = v_rcp(1.0f + v_exp2(fmaf(acc0[r], NLOG2E, sn0)));
        float hn0 = fmaf(g0, hm[ci][0][r], qe * lg0);
        hm[ci][0][r] = hn0; ht[0] = fmaf(qq, hn0, ht[0]);
        float g1 = v_rcp(1.0f + v_exp2(fmaf(acc1[r], NLOG2E, sn1)));
        float hn1 = fmaf(g1, hm[ci][1][r], qe * lg1);
        hm[ci][1][r] = hn1; ht[1] = fmaf(qq, hn1, ht[1]);
        int base = c * 256; int swz = (c & 15) << 4;
        *(uint16_t*)(hwr + base + ((j0 * 2) ^ swz)) = (uint16_t)pkbf(hn0, 0.f);
        *(uint16_t*)(hwr + base + ((j1 * 2) ^ swz)) = (uint16_t)pkbf(hn1, 0.f);
      }
    }
#pragma unroll
    for (int ji = 0; ji < 2; ++ji) {
      float v = ht[ji] + __shfl_xor(ht[ji], 32);
      if (hi == 0) htp[cg][jg * 64 + ji * 32 + lo] = v;
    }
    __syncthreads(); // 4
    // ---- phase R: h_tilde reduce + commit prefetched values
    if (tid < 128) {
      float v = htp[0][tid] + htp[1][tid] + htp[2][tid] + htp[3][tid];
      htld[tid] = v;
      ws[OFF_HT + (b * 127 + s) * DK + tid] = v;
    }
    if (tid < 256) qbuf[(s + 2) % 3][tid] = qv;
    if (tid < 384) rsd[tid >> 7][tid & 127] = rv;
    __syncthreads(); // 5
  }
}

// ---------------- kernel 2: deferred y = mean_j sigmoid(preY + h_tilde @ W5h) ----------------
__global__ __launch_bounds__(128) void k2_y(const float* __restrict__ ws, float* __restrict__ out)
{
  __shared__ float hts[8][128];
  __shared__ float part[2][8];
  int b = blockIdx.x >> 4, ch = blockIdx.x & 15, s0 = ch * 8;
  int j = threadIdx.x;
#pragma unroll
  for (int u = 0; u < 8; ++u) {
    int s = s0 + u;
    hts[u][j] = (s < 127) ? ws[OFF_HT + (b * 127 + s) * DK + j] : 0.f;
  }
  __syncthreads();
  float acc[8];
#pragma unroll
  for (int u = 0; u < 8; ++u) {
    int s = s0 + u;
    acc[u] = (s < 127) ? ws[OFF_PY + (b * 127 + s) * DK + j] : 0.f;
  }
  const float4* w5 = (const float4*)(ws + OFF_WT5 + j * DK);
#pragma unroll 8
  for (int i = 0; i < 32; ++i) {
    float4 w = w5[i];
#pragma unroll
    for (int u = 0; u < 8; ++u) {
      float4 h4 = *(const float4*)&hts[u][4 * i];
      acc[u] += w.x * h4.x + w.y * h4.y + w.z * h4.z + w.w * h4.w;
    }
  }
#pragma unroll
  for (int u = 0; u < 8; ++u) {
    float v = sigm(acc[u]);
#pragma unroll
    for (int off = 32; off >= 1; off >>= 1) v += __shfl_xor(v, off);
    if ((j & 63) == 0) part[j >> 6][u] = v;
  }
  __syncthreads();
  if (j < 8) {
    int s = s0 + j;
    if (s < 127) out[b * S + s + 1] = (part[0][j] + part[1][j]) * (1.0f / 128.0f);
  }
  if (j == 0 && ch == 0) out[b * S] = 0.f;
}

extern "C" void kernel_launch(void* const* d_in, const int* in_sizes, int n_in,
                              void* d_out, int out_size, void* d_ws, size_t ws_size,
                              hipStream_t stream)
{
  (void)in_sizes; (void)n_in; (void)out_size; (void)ws_size;
  const int*   e_data  = (const int*)  d_in[0];
  const int*   at_data = (const int*)  d_in[1];
  const int*   it_data = (const int*)  d_in[2];
  const float* a_data  = (const float*)d_in[3];
  const float* qmat    = (const float*)d_in[4];
  const float* e_E     = (const float*)d_in[5];
  const float* at_E    = (const float*)d_in[6];
  const float* it_E    = (const float*)d_in[7];
  const float* W1 = (const float*)d_in[8];  const float* b1 = (const float*)d_in[9];
  const float* W2 = (const float*)d_in[10]; const float* b2 = (const float*)d_in[11];
  const float* W3 = (const float*)d_in[12]; const float* b3 = (const float*)d_in[13];
  const float* W4 = (const float*)d_in[14]; const float* b4 = (const float*)d_in[15];
  const float* W5 = (const float*)d_in[16]; const float* b5 = (const float*)d_in[17];
  const float* h0 = (const float*)d_in[18];
  float* ws  = (float*)d_ws;
  float* out = (float*)d_out;

  k0_al <<<128, 512, 0, stream>>>(e_data, at_data, a_data, e_E, at_E, W1, b1, ws);
  kT_tr <<<64, 256, 0, stream>>>(W5, ws);
  k1_pre<<<128, 512, 0, stream>>>(e_data, it_data, it_E, e_E, W2, b2, W3, b3, W4, b4, W5, b5, ws);
  kmain <<<32, 512, 0, stream>>>(e_data, qmat, W2, W3, W4, h0, ws, out);
  k2_y  <<<512, 128, 0, stream>>>(ws, out);
}

// Round 4
// 1910.782 us; speedup vs baseline: 1.3523x; 1.3523x over previous
//
#include <hip/hip_runtime.h>
#include <stdint.h>

#define S   128
#define NB  32
#define NC  256
#define DK  128

typedef __bf16 bf16x8 __attribute__((ext_vector_type(8)));
typedef float  f32x16 __attribute__((ext_vector_type(16)));
typedef unsigned int u32x4 __attribute__((ext_vector_type(4)));
static_assert(sizeof(bf16x8) == 16, "bf16x8 size");
static_assert(sizeof(u32x4) == 16, "u32x4 size");

// d_ws layout (float offsets). HT reuses AL region (AL consumed by k1 before kmain writes HT).
#define OFF_AL   0
#define OFF_HT   OFF_AL
#define OFF_P2   524288
#define OFF_P3   1044480
#define OFF_PS   1564672
#define OFF_PY   2084864
#define OFF_WT5  2654208

__device__ __forceinline__ float v_exp2(float x){ float r; asm("v_exp_f32 %0, %1" : "=v"(r) : "v"(x)); return r; }
__device__ __forceinline__ float v_rcp (float x){ float r; asm("v_rcp_f32 %0, %1" : "=v"(r) : "v"(x)); return r; }
__device__ __forceinline__ float sigm(float x){ return v_rcp(1.0f + v_exp2(x * -1.4426950408889634f)); }
__device__ __forceinline__ uint32_t pkbf(float lo, float hi){
  uint32_t r; asm("v_cvt_pk_bf16_f32 %0, %1, %2" : "=v"(r) : "v"(lo), "v"(hi)); return r;
}
__device__ __forceinline__ float bflo(uint32_t w){ return __builtin_bit_cast(float, w << 16); }
__device__ __forceinline__ float bfhi(uint32_t w){ return __builtin_bit_cast(float, w & 0xffff0000u); }
#define NLOG2E (-1.4426950408889634f)

// ---------------- kernel 0: AL = concat(e_emb, at_emb, a*ones50) @ W1 + b1 ----------------
__global__ __launch_bounds__(512) void k0_al(
    const int* __restrict__ e_data, const int* __restrict__ at_data,
    const float* __restrict__ a_data, const float* __restrict__ e_E,
    const float* __restrict__ at_E, const float* __restrict__ W1,
    const float* __restrict__ b1, float* __restrict__ ws)
{
  __shared__ float ein[32][128];
  __shared__ float atin[32][128];
  int b = blockIdx.x >> 2, q4 = blockIdx.x & 3, t0 = q4 * 32;
  for (int idx = threadIdx.x; idx < 32 * 128; idx += 512) {
    int r = idx >> 7, j = idx & 127;
    int ev  = e_data [b * S + t0 + r];
    int atv = at_data[b * S + t0 + r];
    ein [r][j] = e_E [ev  * DK + j];
    atin[r][j] = at_E[atv * DK + j];
  }
  __syncthreads();
  int j = threadIdx.x & 127, tq = threadIdx.x >> 7;
  float w1s = 0.f;
  for (int d = 0; d < 50; ++d) w1s += W1[(256 + d) * DK + j];
  float acc[8];
#pragma unroll
  for (int u = 0; u < 8; ++u) {
    int t = t0 + tq * 8 + u;
    acc[u] = b1[j] + a_data[b * S + t] * w1s;
  }
  for (int k = 0; k < 128; ++k) {
    float w = W1[k * DK + j];
#pragma unroll
    for (int u = 0; u < 8; ++u) acc[u] += ein[tq * 8 + u][k] * w;
  }
  for (int k = 0; k < 128; ++k) {
    float w = W1[(128 + k) * DK + j];
#pragma unroll
    for (int u = 0; u < 8; ++u) acc[u] += atin[tq * 8 + u][k] * w;
  }
#pragma unroll
  for (int u = 0; u < 8; ++u)
    ws[OFF_AL + (b * S + t0 + tq * 8 + u) * DK + j] = acc[u];
}

// ---------------- kernel T: transpose W5 h-block into ws (for k2_y row-dots) ----------------
__global__ __launch_bounds__(256) void kT_tr(const float* __restrict__ W5, float* __restrict__ ws)
{
  int idx = blockIdx.x * 256 + threadIdx.x;   // 0..16383
  int j = idx >> 7, k = idx & 127;
  ws[OFF_WT5 + j * DK + k] = W5[(128 + k) * DK + j];
}

// ---------------- kernel 1: carry-independent per-step preactivations ----------------
__global__ __launch_bounds__(512) void k1_pre(
    const int* __restrict__ e_data, const int* __restrict__ it_data,
    const float* __restrict__ it_E, const float* __restrict__ e_E,
    const float* __restrict__ W2, const float* __restrict__ b2,
    const float* __restrict__ W3, const float* __restrict__ b3,
    const float* __restrict__ W4, const float* __restrict__ b4,
    const float* __restrict__ W5, const float* __restrict__ b5,
    float* __restrict__ ws)
{
  __shared__ float als[33][128];
  __shared__ float its[32][128];
  __shared__ float ens[32][128];
  int b = blockIdx.x >> 2, sh = blockIdx.x & 3, s0 = sh * 32;
  for (int idx = threadIdx.x; idx < 33 * 128; idx += 512) {
    int r = idx >> 7, j = idx & 127;
    int srow = s0 - 1 + r;
    als[r][j] = (srow >= 0) ? ws[OFF_AL + (b * S + srow) * DK + j] : 0.f;
  }
  for (int idx = threadIdx.x; idx < 32 * 128; idx += 512) {
    int r = idx >> 7, j = idx & 127;
    int itv = it_data[b * S + s0 + r];
    its[r][j] = it_E[itv * DK + j];
    int sg = s0 + r + 1; if (sg > 127) sg = 127;
    int ev = e_data[b * S + sg];
    ens[r][j] = e_E[ev * DK + j];
  }
  __syncthreads();
  int j = threadIdx.x & 127, sq = threadIdx.x >> 7;
  float p2[8], p3[8], pS[8], pY[8];
#pragma unroll
  for (int u = 0; u < 8; ++u) { p2[u] = b2[j]; p3[u] = b3[j]; pS[u] = b4[j]; pY[u] = b5[j]; }
  for (int k = 0; k < 128; ++k) {
    float w2 = W2[k * DK + j], w3 = W3[k * DK + j];
#pragma unroll
    for (int u = 0; u < 8; ++u) { float v = als[sq * 8 + u][k]; p2[u] += v * w2; p3[u] += v * w3; }
  }
  for (int k = 0; k < 128; ++k) {
    float w2 = W2[(128 + k) * DK + j], w3 = W3[(128 + k) * DK + j], w4 = W4[(256 + k) * DK + j];
#pragma unroll
    for (int u = 0; u < 8; ++u) { float v = its[sq * 8 + u][k]; p2[u] += v * w2; p3[u] += v * w3; pS[u] += v * w4; }
  }
  for (int k = 0; k < 128; ++k) {
    float w2 = W2[(256 + k) * DK + j], w3 = W3[(256 + k) * DK + j];
#pragma unroll
    for (int u = 0; u < 8; ++u) { float v = als[sq * 8 + u + 1][k]; p2[u] += v * w2; p3[u] += v * w3; }
  }
  for (int k = 0; k < 128; ++k) {
    float w5 = W5[k * DK + j];
#pragma unroll
    for (int u = 0; u < 8; ++u) pY[u] += ens[sq * 8 + u][k] * w5;
  }
#pragma unroll
  for (int u = 0; u < 8; ++u) {
    int s = s0 + sq * 8 + u;
    if (s < 127) {
      int o = (b * 127 + s) * DK + j;
      ws[OFF_P2 + o] = p2[u]; ws[OFF_P3 + o] = p3[u];
      ws[OFF_PS + o] = pS[u]; ws[OFF_PY + o] = pY[u];
    }
  }
}

// ---------------- main recurrent kernel: globally-silent steady-state loop ----------------
// 1 block/batch row, 512 thr. Per step: P1 [8-step refill (1/8 steps) + 32 MFMA + A-dot],
// b1, P2 [LG, 128thr], b2, P3 [B-dot from LDS bf16 W4L], b3, X [sbc gather + gamma/h-update
// + bf16 pack into hsb], b4, R [htld reduce -> LDS HTST].
// wave (cg,jg): cg 0..3 c-band(64), jg 0..1 j-half(64). hm f32 master 64 regs,
// bfr W4h frags 64 regs, Aw packed-bf16 A-dot weights 32 regs.
__global__ __launch_bounds__(512, 2) void kmain(
    const int* __restrict__ e_data, const float* __restrict__ qmat,
    const float* __restrict__ W2, const float* __restrict__ W3,
    const float* __restrict__ W4, const float* __restrict__ h0,
    float* __restrict__ ws)
{
  __shared__ char     hsb[65536];        // h bf16 [c][k] XOR-swizzled (single buffer)
  __shared__ uint32_t W4Lp[64][128];     // W4[128:256] as bf16 pairs [k/2][j]  (32KB)
  __shared__ float    QST[2][8][256];    // staged q rows, double-banked        (16KB)
  __shared__ float    PST[2][3][8][128]; // staged preacts (r2,r3,rS)           (24KB)
  __shared__ float    HTST[8][128];      // h_tilde history for batched flush   (4KB)
  __shared__ float    ap[4][128];
  __shared__ float    sbcp[4][128];
  __shared__ float    LGs[128];
  __shared__ float    htld[128];
  __shared__ float    htp[4][128];

  const int b = blockIdx.x;
  const int tid = threadIdx.x;
  const int lane = tid & 63, wv = tid >> 6;
  const int cg = wv >> 1, jg = wv & 1;
  const int lo = lane & 31, hi = lane >> 5;
  const int j = tid & 127;
  const int am = tid >> 8, akh = (tid >> 7) & 1;   // A-dot slice (matrix, k-half)
  const int kq = tid >> 7;                         // B-dot k-quarter

  // ---- persistent registers ----
  u32x4 bfr[2][8];                                 // W4h B-frags
#pragma unroll
  for (int ji = 0; ji < 2; ++ji) {
    int jc = jg * 64 + ji * 32 + lo;
#pragma unroll
    for (int kk = 0; kk < 8; ++kk) {
      float w[8];
#pragma unroll
      for (int e = 0; e < 8; ++e) w[e] = W4[(kk * 16 + hi * 8 + e) * DK + jc];
      u32x4 d;
      d[0] = pkbf(w[0], w[1]); d[1] = pkbf(w[2], w[3]);
      d[2] = pkbf(w[4], w[5]); d[3] = pkbf(w[6], w[7]);
      bfr[ji][kk] = d;
    }
  }
  uint32_t Aw[32];                                 // packed bf16 pairs of Wm[384+akh*64+k][j]
  {
    const float* Wm = am ? W3 : W2;
#pragma unroll
    for (int i = 0; i < 32; ++i) {
      float w0 = Wm[(384 + akh * 64 + 2 * i) * DK + j];
      float w1 = Wm[(384 + akh * 64 + 2 * i + 1) * DK + j];
      Aw[i] = pkbf(w0, w1);
    }
  }
  float hm[2][2][16];                              // f32 master h
#pragma unroll
  for (int ci = 0; ci < 2; ++ci)
#pragma unroll
    for (int ji = 0; ji < 2; ++ji)
#pragma unroll
      for (int r = 0; r < 16; ++r) {
        int row = (r & 3) + 8 * (r >> 2) + 4 * hi;
        hm[ci][ji][r] = h0[(cg * 64 + ci * 32 + row) * DK + jg * 64 + ji * 32 + lo];
      }

  // ---- prologue LDS fills ----
#pragma unroll
  for (int it = 0; it < 16; ++it) {                // W4Lp
    int idx = tid + it * 512, kp = idx >> 7, jj = idx & 127;
    W4Lp[kp][jj] = pkbf(W4[(128 + 2 * kp) * DK + jj], W4[(128 + 2 * kp + 1) * DK + jj]);
  }
#pragma unroll
  for (int it = 0; it < 4; ++it) {                 // QST bank0 = q[0..7]
    int idx = tid + it * 512, rr = idx >> 8, cc = idx & 255;
    QST[0][rr][cc] = qmat[e_data[b * S + rr] * NC + cc];
  }
#pragma unroll
  for (int it = 0; it < 6; ++it) {                 // PST bank0 = preacts[0..7]
    int idx = tid + it * 512, mm = idx >> 10, rr = (idx >> 7) & 7, jj = idx & 127;
    int off = (mm == 0) ? OFF_P2 : (mm == 1) ? OFF_P3 : OFF_PS;
    PST[0][mm][rr][jj] = ws[off + (b * 127 + rr) * DK + jj];
  }
#pragma unroll
  for (int ci = 0; ci < 2; ++ci)                   // pack h0 into hsb
#pragma unroll
    for (int ji = 0; ji < 2; ++ji)
#pragma unroll
      for (int r = 0; r < 16; ++r) {
        int row = (r & 3) + 8 * (r >> 2) + 4 * hi;
        int c = cg * 64 + ci * 32 + row;
        int jb = (jg * 64 + ji * 32 + lo) * 2;
        *(uint16_t*)(hsb + c * 256 + (jb ^ ((c & 15) << 4))) = (uint16_t)pkbf(hm[ci][ji][r], 0.f);
      }
  __syncthreads();

  // ---- h_tilde_init ----
  {
    float ht0 = 0.f, ht1 = 0.f;
#pragma unroll
    for (int ci = 0; ci < 2; ++ci)
#pragma unroll
      for (int r = 0; r < 16; ++r) {
        int row = (r & 3) + 8 * (r >> 2) + 4 * hi;
        float qv = QST[0][0][cg * 64 + ci * 32 + row];
        ht0 += qv * hm[ci][0][r];
        ht1 += qv * hm[ci][1][r];
      }
    ht0 += __shfl_xor(ht0, 32);
    ht1 += __shfl_xor(ht1, 32);
    if (hi == 0) { htp[cg][jg * 64 + lo] = ht0; htp[cg][jg * 64 + 32 + lo] = ht1; }
  }
  __syncthreads();
  if (tid < 128) htld[tid] = htp[0][tid] + htp[1][tid] + htp[2][tid] + htp[3][tid];
  __syncthreads();

#pragma unroll 1
  for (int s = 0; s < S - 1; ++s) {
    const int u = s & 7, bank = (s >> 3) & 1;

    // ===== P1: refill-issue + MFMA + A-dot + refill-commit =====
    float qld[4], pld[6];
    const bool refill = (u == 0);
    if (refill) {
      if (s > 0) {                                 // flush prev block's h_tilde
#pragma unroll
        for (int it = 0; it < 2; ++it) {
          int idx = tid + it * 512, rr = idx >> 7, jj = idx & 127;
          ws[OFF_HT + (b * 127 + (s - 8) + rr) * DK + jj] = HTST[rr][jj];
        }
      }
#pragma unroll
      for (int it = 0; it < 4; ++it) {             // q rows for steps s+8 .. s+15
        int idx = tid + it * 512, rr = idx >> 8, cc = idx & 255;
        qld[it] = qmat[e_data[b * S + min(s + 8 + rr, S - 1)] * NC + cc];
      }
#pragma unroll
      for (int it = 0; it < 6; ++it) {             // preacts for steps s+8 .. s+15
        int idx = tid + it * 512, mm = idx >> 10, rr = (idx >> 7) & 7, jj = idx & 127;
        int off = (mm == 0) ? OFF_P2 : (mm == 1) ? OFF_P3 : OFF_PS;
        pld[it] = ws[off + (b * 127 + min(s + 8 + rr, S - 2)) * DK + jj];
      }
    }

    // MFMA: pre[c,j] = h_bf16 @ W4h  (acc lives to X)
    f32x16 acc[2][2];
#pragma unroll
    for (int ci = 0; ci < 2; ++ci)
#pragma unroll
      for (int r = 0; r < 16; ++r) { acc[ci][0][r] = 0.f; acc[ci][1][r] = 0.f; }
#pragma unroll
    for (int ci = 0; ci < 2; ++ci) {
      int c = cg * 64 + ci * 32 + lo;
#pragma unroll
      for (int kk = 0; kk < 8; ++kk) {
        bf16x8 af = __builtin_bit_cast(bf16x8,
            *(const u32x4*)(hsb + c * 256 + ((kk * 32 + hi * 16) ^ ((c & 15) << 4))));
        acc[ci][0] = __builtin_amdgcn_mfma_f32_32x32x16_bf16(af, __builtin_bit_cast(bf16x8, bfr[0][kk]), acc[ci][0], 0, 0, 0);
        acc[ci][1] = __builtin_amdgcn_mfma_f32_32x32x16_bf16(af, __builtin_bit_cast(bf16x8, bfr[1][kk]), acc[ci][1], 0, 0, 0);
      }
    }

    // A-dot: ap[m*2+kh][j] = (htld[kh-half] . Wm-col-j)
    {
      float p = 0.f;
#pragma unroll
      for (int t = 0; t < 16; ++t) {
        float4 h4 = *(const float4*)&htld[akh * 64 + 4 * t];
        uint32_t w0 = Aw[2 * t], w1 = Aw[2 * t + 1];
        p += bflo(w0) * h4.x + bfhi(w0) * h4.y + bflo(w1) * h4.z + bfhi(w1) * h4.w;
      }
      ap[am * 2 + akh][j] = p;
    }

    if (refill) {                                  // commit staged data (drains vmcnt once/8 steps)
#pragma unroll
      for (int it = 0; it < 4; ++it) {
        int idx = tid + it * 512, rr = idx >> 8, cc = idx & 255;
        QST[bank ^ 1][rr][cc] = qld[it];
      }
#pragma unroll
      for (int it = 0; it < 6; ++it) {
        int idx = tid + it * 512, mm = idx >> 10, rr = (idx >> 7) & 7, jj = idx & 127;
        PST[bank ^ 1][mm][rr][jj] = pld[it];
      }
    }
    __syncthreads(); // b1

    // ===== P2: LG finish =====
    if (tid < 128) {
      float v2 = PST[bank][0][u][tid] + ap[0][tid] + ap[1][tid];
      float v3 = PST[bank][1][u][tid] + ap[2][tid] + ap[3][tid];
      LGs[tid] = sigm(v3) * sigm(2.f * v2);        // sigmoid(v3)*(tanh(v2)+1)/2
    }
    __syncthreads(); // b2

    // ===== P3: B-dot partials (sbc = rS + W4L . LG) =====
    {
      float pB = 0.f;
#pragma unroll
      for (int t = 0; t < 8; ++t) {
        float4 g4 = *(const float4*)&LGs[kq * 32 + 4 * t];
        uint32_t w0 = W4Lp[kq * 16 + 2 * t][j], w1 = W4Lp[kq * 16 + 2 * t + 1][j];
        pB += bflo(w0) * g4.x + bfhi(w0) * g4.y + bflo(w1) * g4.z + bfhi(w1) * g4.w;
      }
      sbcp[kq][j] = pB;
    }
    __syncthreads(); // b3

    // ===== X: gamma / h-update / pack =====
    {
      const float* qc = &QST[bank][u][0];
      const float* qn = (u < 7) ? &QST[bank][u + 1][0] : &QST[bank ^ 1][0][0];
      int j0 = jg * 64 + lo, j1 = j0 + 32;
      float sb0 = PST[bank][2][u][j0] + sbcp[0][j0] + sbcp[1][j0] + sbcp[2][j0] + sbcp[3][j0];
      float sb1 = PST[bank][2][u][j1] + sbcp[0][j1] + sbcp[1][j1] + sbcp[2][j1] + sbcp[3][j1];
      float sn0 = sb0 * NLOG2E, sn1 = sb1 * NLOG2E;
      float lg0 = LGs[j0], lg1 = LGs[j1];
      float ht0 = 0.f, ht1 = 0.f;
#pragma unroll
      for (int ci = 0; ci < 2; ++ci) {
#pragma unroll
        for (int r = 0; r < 16; ++r) {
          int row = (r & 3) + 8 * (r >> 2) + 4 * hi;
          int c = cg * 64 + ci * 32 + row;
          float qe = qc[c], qq = qn[c];
          float g0 = v_rcp(1.0f + v_exp2(fmaf(acc[ci][0][r], NLOG2E, sn0)));
          float hn0 = fmaf(g0, hm[ci][0][r], qe * lg0);
          hm[ci][0][r] = hn0; ht0 = fmaf(qq, hn0, ht0);
          float g1 = v_rcp(1.0f + v_exp2(fmaf(acc[ci][1][r], NLOG2E, sn1)));
          float hn1 = fmaf(g1, hm[ci][1][r], qe * lg1);
          hm[ci][1][r] = hn1; ht1 = fmaf(qq, hn1, ht1);
          int base = c * 256, swz = (c & 15) << 4;
          *(uint16_t*)(hsb + base + ((j0 * 2) ^ swz)) = (uint16_t)pkbf(hn0, 0.f);
          *(uint16_t*)(hsb + base + ((j1 * 2) ^ swz)) = (uint16_t)pkbf(hn1, 0.f);
        }
      }
      ht0 += __shfl_xor(ht0, 32);
      ht1 += __shfl_xor(ht1, 32);
      if (hi == 0) { htp[cg][j0] = ht0; htp[cg][j1] = ht1; }
    }
    __syncthreads(); // b4

    // ===== R: h_tilde reduce =====
    if (tid < 128) {
      float v = htp[0][tid] + htp[1][tid] + htp[2][tid] + htp[3][tid];
      htld[tid] = v;
      HTST[u][tid] = v;
    }
    __syncthreads(); // b5
  }

  // final flush: steps 120..126 (rows 0..6 of last block)
#pragma unroll
  for (int it = 0; it < 2; ++it) {
    int idx = tid + it * 512;
    if (idx < 7 * 128) {
      int rr = idx >> 7, jj = idx & 127;
      ws[OFF_HT + (b * 127 + 120 + rr) * DK + jj] = HTST[rr][jj];
    }
  }
}

// ---------------- kernel 2: deferred y = mean_j sigmoid(preY + h_tilde @ W5h) ----------------
__global__ __launch_bounds__(128) void k2_y(const float* __restrict__ ws, float* __restrict__ out)
{
  __shared__ float hts[8][128];
  __shared__ float part[2][8];
  int b = blockIdx.x >> 4, ch = blockIdx.x & 15, s0 = ch * 8;
  int j = threadIdx.x;
#pragma unroll
  for (int u = 0; u < 8; ++u) {
    int s = s0 + u;
    hts[u][j] = (s < 127) ? ws[OFF_HT + (b * 127 + s) * DK + j] : 0.f;
  }
  __syncthreads();
  float acc[8];
#pragma unroll
  for (int u = 0; u < 8; ++u) {
    int s = s0 + u;
    acc[u] = (s < 127) ? ws[OFF_PY + (b * 127 + s) * DK + j] : 0.f;
  }
  const float4* w5 = (const float4*)(ws + OFF_WT5 + j * DK);
#pragma unroll 8
  for (int i = 0; i < 32; ++i) {
    float4 w = w5[i];
#pragma unroll
    for (int u = 0; u < 8; ++u) {
      float4 h4 = *(const float4*)&hts[u][4 * i];
      acc[u] += w.x * h4.x + w.y * h4.y + w.z * h4.z + w.w * h4.w;
    }
  }
#pragma unroll
  for (int u = 0; u < 8; ++u) {
    float v = sigm(acc[u]);
#pragma unroll
    for (int off = 32; off >= 1; off >>= 1) v += __shfl_xor(v, off);
    if ((j & 63) == 0) part[j >> 6][u] = v;
  }
  __syncthreads();
  if (j < 8) {
    int s = s0 + j;
    if (s < 127) out[b * S + s + 1] = (part[0][j] + part[1][j]) * (1.0f / 128.0f);
  }
  if (j == 0 && ch == 0) out[b * S] = 0.f;
}

extern "C" void kernel_launch(void* const* d_in, const int* in_sizes, int n_in,
                              void* d_out, int out_size, void* d_ws, size_t ws_size,
                              hipStream_t stream)
{
  (void)in_sizes; (void)n_in; (void)out_size; (void)ws_size;
  const int*   e_data  = (const int*)  d_in[0];
  const int*   at_data = (const int*)  d_in[1];
  const int*   it_data = (const int*)  d_in[2];
  const float* a_data  = (const float*)d_in[3];
  const float* qmat    = (const float*)d_in[4];
  const float* e_E     = (const float*)d_in[5];
  const float* at_E    = (const float*)d_in[6];
  const float* it_E    = (const float*)d_in[7];
  const float* W1 = (const float*)d_in[8];  const float* b1 = (const float*)d_in[9];
  const float* W2 = (const float*)d_in[10]; const float* b2 = (const float*)d_in[11];
  const float* W3 = (const float*)d_in[12]; const float* b3 = (const float*)d_in[13];
  const float* W4 = (const float*)d_in[14]; const float* b4 = (const float*)d_in[15];
  const float* W5 = (const float*)d_in[16]; const float* b5 = (const float*)d_in[17];
  const float* h0 = (const float*)d_in[18];
  float* ws  = (float*)d_ws;
  float* out = (float*)d_out;

  k0_al <<<128, 512, 0, stream>>>(e_data, at_data, a_data, e_E, at_E, W1, b1, ws);
  kT_tr <<<64, 256, 0, stream>>>(W5, ws);
  k1_pre<<<128, 512, 0, stream>>>(e_data, it_data, it_E, e_E, W2, b2, W3, b3, W4, b4, W5, b5, ws);
  kmain <<<32, 512, 0, stream>>>(e_data, qmat, W2, W3, W4, h0, ws);
  k2_y  <<<512, 128, 0, stream>>>(ws, out);
}

// Round 5
// 1200.616 us; speedup vs baseline: 2.1523x; 1.5915x over previous
//
#include <hip/hip_runtime.h>
#include <stdint.h>

#define S   128
#define NB  32
#define NC  256
#define DK  128

typedef __bf16 bf16x8 __attribute__((ext_vector_type(8)));
typedef float  f32x16 __attribute__((ext_vector_type(16)));
typedef unsigned int u32x4 __attribute__((ext_vector_type(4)));
static_assert(sizeof(bf16x8) == 16, "bf16x8 size");
static_assert(sizeof(u32x4) == 16, "u32x4 size");

// d_ws layout (float offsets). HT reuses AL region (AL consumed by k1 before kmain writes HT).
#define OFF_AL   0
#define OFF_HT   OFF_AL
#define OFF_P2   524288
#define OFF_P3   1044480
#define OFF_PS   1564672
#define OFF_PY   2084864
#define OFF_WT5  2654208

__device__ __forceinline__ float v_exp2(float x){ float r; asm("v_exp_f32 %0, %1" : "=v"(r) : "v"(x)); return r; }
__device__ __forceinline__ float v_rcp (float x){ float r; asm("v_rcp_f32 %0, %1" : "=v"(r) : "v"(x)); return r; }
__device__ __forceinline__ float sigm(float x){ return v_rcp(1.0f + v_exp2(x * -1.4426950408889634f)); }
__device__ __forceinline__ uint32_t pkbf(float lo, float hi){
  uint32_t r; asm("v_cvt_pk_bf16_f32 %0, %1, %2" : "=v"(r) : "v"(lo), "v"(hi)); return r;
}
__device__ __forceinline__ float bflo(uint32_t w){ return __builtin_bit_cast(float, w << 16); }
__device__ __forceinline__ float bfhi(uint32_t w){ return __builtin_bit_cast(float, w & 0xffff0000u); }
#define NLOG2E (-1.4426950408889634f)

// ---------------- kernel 0: AL = concat(e_emb, at_emb, a*ones50) @ W1 + b1 ----------------
__global__ __launch_bounds__(512) void k0_al(
    const int* __restrict__ e_data, const int* __restrict__ at_data,
    const float* __restrict__ a_data, const float* __restrict__ e_E,
    const float* __restrict__ at_E, const float* __restrict__ W1,
    const float* __restrict__ b1, float* __restrict__ ws)
{
  __shared__ float ein[32][128];
  __shared__ float atin[32][128];
  int b = blockIdx.x >> 2, q4 = blockIdx.x & 3, t0 = q4 * 32;
  for (int idx = threadIdx.x; idx < 32 * 128; idx += 512) {
    int r = idx >> 7, j = idx & 127;
    int ev  = e_data [b * S + t0 + r];
    int atv = at_data[b * S + t0 + r];
    ein [r][j] = e_E [ev  * DK + j];
    atin[r][j] = at_E[atv * DK + j];
  }
  __syncthreads();
  int j = threadIdx.x & 127, tq = threadIdx.x >> 7;
  float w1s = 0.f;
  for (int d = 0; d < 50; ++d) w1s += W1[(256 + d) * DK + j];
  float acc[8];
#pragma unroll
  for (int u = 0; u < 8; ++u) {
    int t = t0 + tq * 8 + u;
    acc[u] = b1[j] + a_data[b * S + t] * w1s;
  }
  for (int k = 0; k < 128; ++k) {
    float w = W1[k * DK + j];
#pragma unroll
    for (int u = 0; u < 8; ++u) acc[u] += ein[tq * 8 + u][k] * w;
  }
  for (int k = 0; k < 128; ++k) {
    float w = W1[(128 + k) * DK + j];
#pragma unroll
    for (int u = 0; u < 8; ++u) acc[u] += atin[tq * 8 + u][k] * w;
  }
#pragma unroll
  for (int u = 0; u < 8; ++u)
    ws[OFF_AL + (b * S + t0 + tq * 8 + u) * DK + j] = acc[u];
}

// ---------------- kernel T: transpose W5 h-block into ws (for k2_y row-dots) ----------------
__global__ __launch_bounds__(256) void kT_tr(const float* __restrict__ W5, float* __restrict__ ws)
{
  int idx = blockIdx.x * 256 + threadIdx.x;   // 0..16383
  int j = idx >> 7, k = idx & 127;
  ws[OFF_WT5 + j * DK + k] = W5[(128 + k) * DK + j];
}

// ---------------- kernel 1: carry-independent per-step preactivations ----------------
__global__ __launch_bounds__(512) void k1_pre(
    const int* __restrict__ e_data, const int* __restrict__ it_data,
    const float* __restrict__ it_E, const float* __restrict__ e_E,
    const float* __restrict__ W2, const float* __restrict__ b2,
    const float* __restrict__ W3, const float* __restrict__ b3,
    const float* __restrict__ W4, const float* __restrict__ b4,
    const float* __restrict__ W5, const float* __restrict__ b5,
    float* __restrict__ ws)
{
  __shared__ float als[33][128];
  __shared__ float its[32][128];
  __shared__ float ens[32][128];
  int b = blockIdx.x >> 2, sh = blockIdx.x & 3, s0 = sh * 32;
  for (int idx = threadIdx.x; idx < 33 * 128; idx += 512) {
    int r = idx >> 7, j = idx & 127;
    int srow = s0 - 1 + r;
    als[r][j] = (srow >= 0) ? ws[OFF_AL + (b * S + srow) * DK + j] : 0.f;
  }
  for (int idx = threadIdx.x; idx < 32 * 128; idx += 512) {
    int r = idx >> 7, j = idx & 127;
    int itv = it_data[b * S + s0 + r];
    its[r][j] = it_E[itv * DK + j];
    int sg = s0 + r + 1; if (sg > 127) sg = 127;
    int ev = e_data[b * S + sg];
    ens[r][j] = e_E[ev * DK + j];
  }
  __syncthreads();
  int j = threadIdx.x & 127, sq = threadIdx.x >> 7;
  float p2[8], p3[8], pS[8], pY[8];
#pragma unroll
  for (int u = 0; u < 8; ++u) { p2[u] = b2[j]; p3[u] = b3[j]; pS[u] = b4[j]; pY[u] = b5[j]; }
  for (int k = 0; k < 128; ++k) {
    float w2 = W2[k * DK + j], w3 = W3[k * DK + j];
#pragma unroll
    for (int u = 0; u < 8; ++u) { float v = als[sq * 8 + u][k]; p2[u] += v * w2; p3[u] += v * w3; }
  }
  for (int k = 0; k < 128; ++k) {
    float w2 = W2[(128 + k) * DK + j], w3 = W3[(128 + k) * DK + j], w4 = W4[(256 + k) * DK + j];
#pragma unroll
    for (int u = 0; u < 8; ++u) { float v = its[sq * 8 + u][k]; p2[u] += v * w2; p3[u] += v * w3; pS[u] += v * w4; }
  }
  for (int k = 0; k < 128; ++k) {
    float w2 = W2[(256 + k) * DK + j], w3 = W3[(256 + k) * DK + j];
#pragma unroll
    for (int u = 0; u < 8; ++u) { float v = als[sq * 8 + u + 1][k]; p2[u] += v * w2; p3[u] += v * w3; }
  }
  for (int k = 0; k < 128; ++k) {
    float w5 = W5[k * DK + j];
#pragma unroll
    for (int u = 0; u < 8; ++u) pY[u] += ens[sq * 8 + u][k] * w5;
  }
#pragma unroll
  for (int u = 0; u < 8; ++u) {
    int s = s0 + sq * 8 + u;
    if (s < 127) {
      int o = (b * 127 + s) * DK + j;
      ws[OFF_P2 + o] = p2[u]; ws[OFF_P3 + o] = p3[u];
      ws[OFF_PS + o] = pS[u]; ws[OFF_PY + o] = pY[u];
    }
  }
}

// ---------------- main recurrent kernel: silent loop + low register pressure ----------------
// 1 block/batch row, 512 thr, 5 barriers/step. Arch-VGPR live set kept < 128:
// hm (f32 master h, 64) + Aw (A-dot bf16 weights, 32) + temps; acc (64) in AGPRs;
// W4h MFMA B-frags in LDS (W4B, frag layout); W4L B-dot weights in LDS (bf16 pairs).
// Staging (q rows, preacts) double-banked 4 steps deep -> global traffic 1 step in 4.
__global__ __launch_bounds__(512, 2) void kmain(
    const int* __restrict__ e_data, const float* __restrict__ qmat,
    const float* __restrict__ W2, const float* __restrict__ W3,
    const float* __restrict__ W4, const float* __restrict__ h0,
    float* __restrict__ ws)
{
  __shared__ char     hsb[65536];        // h bf16 [c][k] XOR-swizzled (single buffer)
  __shared__ uint32_t W4Lp[64][128];     // W4[128:256] bf16 pairs [k/2][j]          (32KB)
  __shared__ u32x4    W4B[4][8][64];     // W4[0:128] MFMA B-frags [jb][kk][lane]    (32KB)
  __shared__ float    QST[2][4][256];    // staged q rows                            (8KB)
  __shared__ float    PST[2][3][4][128]; // staged preacts (r2,r3,rS)                (12KB)
  __shared__ float    HTST[4][128];      // h_tilde history for batched flush        (2KB)
  __shared__ float    ap[4][128];
  __shared__ float    sbcp[4][128];
  __shared__ float    LGs[128];
  __shared__ float    htld[128];
  __shared__ float    htp[4][128];

  const int b = blockIdx.x;
  const int tid = threadIdx.x;
  const int lane = tid & 63, wv = tid >> 6;
  const int cg = wv >> 1, jg = wv & 1;
  const int lo = lane & 31, hi = lane >> 5;
  const int j = tid & 127;
  const int am = tid >> 8, akh = (tid >> 7) & 1;   // A-dot slice (matrix, k-half)
  const int kq = tid >> 7;                         // B-dot k-quarter

  // ---- persistent registers: Aw (32) + hm (64) ----
  uint32_t Aw[32];
  {
    const float* Wm = am ? W3 : W2;
#pragma unroll
    for (int i = 0; i < 32; ++i) {
      float w0 = Wm[(384 + akh * 64 + 2 * i) * DK + j];
      float w1 = Wm[(384 + akh * 64 + 2 * i + 1) * DK + j];
      Aw[i] = pkbf(w0, w1);
    }
  }
  float hm[2][2][16];
#pragma unroll
  for (int ci = 0; ci < 2; ++ci)
#pragma unroll
    for (int ji = 0; ji < 2; ++ji)
#pragma unroll
      for (int r = 0; r < 16; ++r) {
        int row = (r & 3) + 8 * (r >> 2) + 4 * hi;
        hm[ci][ji][r] = h0[(cg * 64 + ci * 32 + row) * DK + jg * 64 + ji * 32 + lo];
      }

  // ---- prologue LDS fills ----
#pragma unroll
  for (int it = 0; it < 16; ++it) {                // W4Lp: bf16 pairs of W4 rows 128..255
    int idx = tid + it * 512, kp = idx >> 7, jj = idx & 127;
    W4Lp[kp][jj] = pkbf(W4[(128 + 2 * kp) * DK + jj], W4[(128 + 2 * kp + 1) * DK + jj]);
  }
  {
    uint32_t* w4b = (uint32_t*)&W4B[0][0][0];
#pragma unroll
    for (int it = 0; it < 16; ++it) {              // W4B: frag layout of W4 rows 0..127
      int idx = tid + it * 512;                    // 0..8191
      int w = idx & 3, l = (idx >> 2) & 63, kk = (idx >> 8) & 7, jb = idx >> 11;
      int llo = l & 31, lhi = l >> 5;
      int row = kk * 16 + lhi * 8 + 2 * w, col = jb * 32 + llo;
      w4b[idx] = pkbf(W4[row * DK + col], W4[(row + 1) * DK + col]);
    }
  }
#pragma unroll
  for (int it = 0; it < 2; ++it) {                 // QST bank0 = q[0..3]
    int idx = tid + it * 512, rr = idx >> 8, cc = idx & 255;
    QST[0][rr][cc] = qmat[e_data[b * S + rr] * NC + cc];
  }
#pragma unroll
  for (int it = 0; it < 3; ++it) {                 // PST bank0 = preacts[0..3]
    int idx = tid + it * 512, mm = idx >> 9, rr = (idx >> 7) & 3, jj = idx & 127;
    int off = (mm == 0) ? OFF_P2 : (mm == 1) ? OFF_P3 : OFF_PS;
    PST[0][mm][rr][jj] = ws[off + (b * 127 + rr) * DK + jj];
  }
#pragma unroll
  for (int ci = 0; ci < 2; ++ci)                   // pack h0 into hsb
#pragma unroll
    for (int ji = 0; ji < 2; ++ji)
#pragma unroll
      for (int r = 0; r < 16; ++r) {
        int row = (r & 3) + 8 * (r >> 2) + 4 * hi;
        int c = cg * 64 + ci * 32 + row;
        int jb = (jg * 64 + ji * 32 + lo) * 2;
        *(uint16_t*)(hsb + c * 256 + (jb ^ ((c & 15) << 4))) = (uint16_t)pkbf(hm[ci][ji][r], 0.f);
      }
  __syncthreads();

  // ---- h_tilde_init ----
  {
    float ht0 = 0.f, ht1 = 0.f;
#pragma unroll
    for (int ci = 0; ci < 2; ++ci)
#pragma unroll
      for (int r = 0; r < 16; ++r) {
        int row = (r & 3) + 8 * (r >> 2) + 4 * hi;
        float qv = QST[0][0][cg * 64 + ci * 32 + row];
        ht0 += qv * hm[ci][0][r];
        ht1 += qv * hm[ci][1][r];
      }
    ht0 += __shfl_xor(ht0, 32);
    ht1 += __shfl_xor(ht1, 32);
    if (hi == 0) { htp[cg][jg * 64 + lo] = ht0; htp[cg][jg * 64 + 32 + lo] = ht1; }
  }
  __syncthreads();
  if (tid < 128) htld[tid] = htp[0][tid] + htp[1][tid] + htp[2][tid] + htp[3][tid];
  __syncthreads();

#pragma unroll 1
  for (int s = 0; s < S - 1; ++s) {
    const int u = s & 3, bank = (s >> 2) & 1;
    const bool refill = (u == 0);

    // ===== P1: refill-issue + MFMA (B from LDS) + A-dot + refill-commit =====
    float qld[2], pld[3];
    if (refill) {
      if (s > 0) {                                 // flush prev 4 steps' h_tilde
        int rr = tid >> 7, jj = tid & 127;
        ws[OFF_HT + (b * 127 + (s - 4) + rr) * DK + jj] = HTST[rr][jj];
      }
#pragma unroll
      for (int it = 0; it < 2; ++it) {             // q rows for steps s+4 .. s+7
        int idx = tid + it * 512, rr = idx >> 8, cc = idx & 255;
        qld[it] = qmat[e_data[b * S + min(s + 4 + rr, S - 1)] * NC + cc];
      }
#pragma unroll
      for (int it = 0; it < 3; ++it) {             // preacts for steps s+4 .. s+7
        int idx = tid + it * 512, mm = idx >> 9, rr = (idx >> 7) & 3, jj = idx & 127;
        int off = (mm == 0) ? OFF_P2 : (mm == 1) ? OFF_P3 : OFF_PS;
        pld[it] = ws[off + (b * 127 + min(s + 4 + rr, S - 2)) * DK + jj];
      }
    }

    // MFMA: pre[c,j] = h_bf16 @ W4h ; A-frags from hsb, B-frags from W4B LDS
    f32x16 acc[2][2];
#pragma unroll
    for (int ci = 0; ci < 2; ++ci)
#pragma unroll
      for (int r = 0; r < 16; ++r) { acc[ci][0][r] = 0.f; acc[ci][1][r] = 0.f; }
#pragma unroll
    for (int kk = 0; kk < 8; ++kk) {
      u32x4 bf0 = W4B[jg * 2 + 0][kk][lane];
      u32x4 bf1 = W4B[jg * 2 + 1][kk][lane];
#pragma unroll
      for (int ci = 0; ci < 2; ++ci) {
        int c = cg * 64 + ci * 32 + lo;
        bf16x8 af = __builtin_bit_cast(bf16x8,
            *(const u32x4*)(hsb + c * 256 + ((kk * 32 + hi * 16) ^ ((c & 15) << 4))));
        acc[ci][0] = __builtin_amdgcn_mfma_f32_32x32x16_bf16(af, __builtin_bit_cast(bf16x8, bf0), acc[ci][0], 0, 0, 0);
        acc[ci][1] = __builtin_amdgcn_mfma_f32_32x32x16_bf16(af, __builtin_bit_cast(bf16x8, bf1), acc[ci][1], 0, 0, 0);
      }
    }

    // A-dot: ap[m*2+kh][j] = htld[kh-half] . Wm-col-j
    {
      float p = 0.f;
#pragma unroll
      for (int t = 0; t < 16; ++t) {
        float4 h4 = *(const float4*)&htld[akh * 64 + 4 * t];
        uint32_t w0 = Aw[2 * t], w1 = Aw[2 * t + 1];
        p += bflo(w0) * h4.x + bfhi(w0) * h4.y + bflo(w1) * h4.z + bfhi(w1) * h4.w;
      }
      ap[am * 2 + akh][j] = p;
    }

    if (refill) {                                  // commit staged data
#pragma unroll
      for (int it = 0; it < 2; ++it) {
        int idx = tid + it * 512, rr = idx >> 8, cc = idx & 255;
        QST[bank ^ 1][rr][cc] = qld[it];
      }
#pragma unroll
      for (int it = 0; it < 3; ++it) {
        int idx = tid + it * 512, mm = idx >> 9, rr = (idx >> 7) & 3, jj = idx & 127;
        PST[bank ^ 1][mm][rr][jj] = pld[it];
      }
    }
    __syncthreads(); // b1

    // ===== P2: LG finish =====
    if (tid < 128) {
      float v2 = PST[bank][0][u][tid] + ap[0][tid] + ap[1][tid];
      float v3 = PST[bank][1][u][tid] + ap[2][tid] + ap[3][tid];
      LGs[tid] = sigm(v3) * sigm(2.f * v2);        // sigmoid(v3)*(tanh(v2)+1)/2
    }
    __syncthreads(); // b2

    // ===== P3: B-dot partials (sbc = rS + W4L . LG) =====
    {
      float pB = 0.f;
#pragma unroll
      for (int t = 0; t < 8; ++t) {
        float4 g4 = *(const float4*)&LGs[kq * 32 + 4 * t];
        uint32_t w0 = W4Lp[kq * 16 + 2 * t][j], w1 = W4Lp[kq * 16 + 2 * t + 1][j];
        pB += bflo(w0) * g4.x + bfhi(w0) * g4.y + bflo(w1) * g4.z + bfhi(w1) * g4.w;
      }
      sbcp[kq][j] = pB;
    }
    __syncthreads(); // b3

    // ===== X: gamma / h-update / pack =====
    {
      const float* qc = &QST[bank][u][0];
      const float* qn = (u < 3) ? &QST[bank][u + 1][0] : &QST[bank ^ 1][0][0];
      int j0 = jg * 64 + lo, j1 = j0 + 32;
      float sb0 = PST[bank][2][u][j0] + sbcp[0][j0] + sbcp[1][j0] + sbcp[2][j0] + sbcp[3][j0];
      float sb1 = PST[bank][2][u][j1] + sbcp[0][j1] + sbcp[1][j1] + sbcp[2][j1] + sbcp[3][j1];
      float sn0 = sb0 * NLOG2E, sn1 = sb1 * NLOG2E;
      float lg0 = LGs[j0], lg1 = LGs[j1];
      float ht0 = 0.f, ht1 = 0.f;
#pragma unroll
      for (int ci = 0; ci < 2; ++ci) {
#pragma unroll
        for (int r = 0; r < 16; ++r) {
          int row = (r & 3) + 8 * (r >> 2) + 4 * hi;
          int c = cg * 64 + ci * 32 + row;
          float qe = qc[c], qq = qn[c];
          float g0 = v_rcp(1.0f + v_exp2(fmaf(acc[ci][0][r], NLOG2E, sn0)));
          float hn0 = fmaf(g0, hm[ci][0][r], qe * lg0);
          hm[ci][0][r] = hn0; ht0 = fmaf(qq, hn0, ht0);
          float g1 = v_rcp(1.0f + v_exp2(fmaf(acc[ci][1][r], NLOG2E, sn1)));
          float hn1 = fmaf(g1, hm[ci][1][r], qe * lg1);
          hm[ci][1][r] = hn1; ht1 = fmaf(qq, hn1, ht1);
          int base = c * 256, swz = (c & 15) << 4;
          *(uint16_t*)(hsb + base + ((j0 * 2) ^ swz)) = (uint16_t)pkbf(hn0, 0.f);
          *(uint16_t*)(hsb + base + ((j1 * 2) ^ swz)) = (uint16_t)pkbf(hn1, 0.f);
        }
      }
      ht0 += __shfl_xor(ht0, 32);
      ht1 += __shfl_xor(ht1, 32);
      if (hi == 0) { htp[cg][j0] = ht0; htp[cg][j1] = ht1; }
    }
    __syncthreads(); // b4

    // ===== R: h_tilde reduce =====
    if (tid < 128) {
      float v = htp[0][tid] + htp[1][tid] + htp[2][tid] + htp[3][tid];
      htld[tid] = v;
      HTST[u][tid] = v;
    }
    __syncthreads(); // b5
  }

  // final flush: steps 124..126 (HTST rows 0..2)
  if (tid < 3 * 128) {
    int rr = tid >> 7, jj = tid & 127;
    ws[OFF_HT + (b * 127 + 124 + rr) * DK + jj] = HTST[rr][jj];
  }
}

// ---------------- kernel 2: deferred y = mean_j sigmoid(preY + h_tilde @ W5h) ----------------
__global__ __launch_bounds__(128) void k2_y(const float* __restrict__ ws, float* __restrict__ out)
{
  __shared__ float hts[8][128];
  __shared__ float part[2][8];
  int b = blockIdx.x >> 4, ch = blockIdx.x & 15, s0 = ch * 8;
  int j = threadIdx.x;
#pragma unroll
  for (int u = 0; u < 8; ++u) {
    int s = s0 + u;
    hts[u][j] = (s < 127) ? ws[OFF_HT + (b * 127 + s) * DK + j] : 0.f;
  }
  __syncthreads();
  float acc[8];
#pragma unroll
  for (int u = 0; u < 8; ++u) {
    int s = s0 + u;
    acc[u] = (s < 127) ? ws[OFF_PY + (b * 127 + s) * DK + j] : 0.f;
  }
  const float4* w5 = (const float4*)(ws + OFF_WT5 + j * DK);
#pragma unroll 8
  for (int i = 0; i < 32; ++i) {
    float4 w = w5[i];
#pragma unroll
    for (int u = 0; u < 8; ++u) {
      float4 h4 = *(const float4*)&hts[u][4 * i];
      acc[u] += w.x * h4.x + w.y * h4.y + w.z * h4.z + w.w * h4.w;
    }
  }
#pragma unroll
  for (int u = 0; u < 8; ++u) {
    float v = sigm(acc[u]);
#pragma unroll
    for (int off = 32; off >= 1; off >>= 1) v += __shfl_xor(v, off);
    if ((j & 63) == 0) part[j >> 6][u] = v;
  }
  __syncthreads();
  if (j < 8) {
    int s = s0 + j;
    if (s < 127) out[b * S + s + 1] = (part[0][j] + part[1][j]) * (1.0f / 128.0f);
  }
  if (j == 0 && ch == 0) out[b * S] = 0.f;
}

extern "C" void kernel_launch(void* const* d_in, const int* in_sizes, int n_in,
                              void* d_out, int out_size, void* d_ws, size_t ws_size,
                              hipStream_t stream)
{
  (void)in_sizes; (void)n_in; (void)out_size; (void)ws_size;
  const int*   e_data  = (const int*)  d_in[0];
  const int*   at_data = (const int*)  d_in[1];
  const int*   it_data = (const int*)  d_in[2];
  const float* a_data  = (const float*)d_in[3];
  const float* qmat    = (const float*)d_in[4];
  const float* e_E     = (const float*)d_in[5];
  const float* at_E    = (const float*)d_in[6];
  const float* it_E    = (const float*)d_in[7];
  const float* W1 = (const float*)d_in[8];  const float* b1 = (const float*)d_in[9];
  const float* W2 = (const float*)d_in[10]; const float* b2 = (const float*)d_in[11];
  const float* W3 = (const float*)d_in[12]; const float* b3 = (const float*)d_in[13];
  const float* W4 = (const float*)d_in[14]; const float* b4 = (const float*)d_in[15];
  const float* W5 = (const float*)d_in[16]; const float* b5 = (const float*)d_in[17];
  const float* h0 = (const float*)d_in[18];
  float* ws  = (float*)d_ws;
  float* out = (float*)d_out;

  k0_al <<<128, 512, 0, stream>>>(e_data, at_data, a_data, e_E, at_E, W1, b1, ws);
  kT_tr <<<64, 256, 0, stream>>>(W5, ws);
  k1_pre<<<128, 512, 0, stream>>>(e_data, it_data, it_E, e_E, W2, b2, W3, b3, W4, b4, W5, b5, ws);
  kmain <<<32, 512, 0, stream>>>(e_data, qmat, W2, W3, W4, h0, ws);
  k2_y  <<<512, 128, 0, stream>>>(ws, out);
}

// Round 6
// 1176.591 us; speedup vs baseline: 2.1962x; 1.0204x over previous
//
#include <hip/hip_runtime.h>
#include <stdint.h>

#define S   128
#define NB  32
#define NC  256
#define DK  128

typedef __bf16 bf16x8 __attribute__((ext_vector_type(8)));
typedef float  f32x16 __attribute__((ext_vector_type(16)));
typedef unsigned int u32x4 __attribute__((ext_vector_type(4)));
static_assert(sizeof(bf16x8) == 16, "bf16x8 size");
static_assert(sizeof(u32x4) == 16, "u32x4 size");

// d_ws layout (float offsets). HT reuses AL region (AL consumed by k1 before kmain writes HT).
#define OFF_AL   0
#define OFF_HT   OFF_AL
#define OFF_P2   524288
#define OFF_P3   1044480
#define OFF_PS   1564672
#define OFF_PY   2084864
#define OFF_WT5  2654208

__device__ __forceinline__ float v_exp2(float x){ float r; asm("v_exp_f32 %0, %1" : "=v"(r) : "v"(x)); return r; }
__device__ __forceinline__ float v_rcp (float x){ float r; asm("v_rcp_f32 %0, %1" : "=v"(r) : "v"(x)); return r; }
__device__ __forceinline__ float sigm(float x){ return v_rcp(1.0f + v_exp2(x * -1.4426950408889634f)); }
__device__ __forceinline__ uint32_t pkbf(float lo, float hi){
  uint32_t r; asm("v_cvt_pk_bf16_f32 %0, %1, %2" : "=v"(r) : "v"(lo), "v"(hi)); return r;
}
__device__ __forceinline__ float bflo(uint32_t w){ return __builtin_bit_cast(float, w << 16); }
__device__ __forceinline__ float bfhi(uint32_t w){ return __builtin_bit_cast(float, w & 0xffff0000u); }
#define NLOG2E (-1.4426950408889634f)

// ---------------- kernel 0: AL = concat(e_emb, at_emb, a*ones50) @ W1 + b1 ----------------
__global__ __launch_bounds__(512) void k0_al(
    const int* __restrict__ e_data, const int* __restrict__ at_data,
    const float* __restrict__ a_data, const float* __restrict__ e_E,
    const float* __restrict__ at_E, const float* __restrict__ W1,
    const float* __restrict__ b1, float* __restrict__ ws)
{
  __shared__ float ein[32][128];
  __shared__ float atin[32][128];
  int b = blockIdx.x >> 2, q4 = blockIdx.x & 3, t0 = q4 * 32;
  for (int idx = threadIdx.x; idx < 32 * 128; idx += 512) {
    int r = idx >> 7, j = idx & 127;
    int ev  = e_data [b * S + t0 + r];
    int atv = at_data[b * S + t0 + r];
    ein [r][j] = e_E [ev  * DK + j];
    atin[r][j] = at_E[atv * DK + j];
  }
  __syncthreads();
  int j = threadIdx.x & 127, tq = threadIdx.x >> 7;
  float w1s = 0.f;
  for (int d = 0; d < 50; ++d) w1s += W1[(256 + d) * DK + j];
  float acc[8];
#pragma unroll
  for (int u = 0; u < 8; ++u) {
    int t = t0 + tq * 8 + u;
    acc[u] = b1[j] + a_data[b * S + t] * w1s;
  }
  for (int k = 0; k < 128; ++k) {
    float w = W1[k * DK + j];
#pragma unroll
    for (int u = 0; u < 8; ++u) acc[u] += ein[tq * 8 + u][k] * w;
  }
  for (int k = 0; k < 128; ++k) {
    float w = W1[(128 + k) * DK + j];
#pragma unroll
    for (int u = 0; u < 8; ++u) acc[u] += atin[tq * 8 + u][k] * w;
  }
#pragma unroll
  for (int u = 0; u < 8; ++u)
    ws[OFF_AL + (b * S + t0 + tq * 8 + u) * DK + j] = acc[u];
}

// ---------------- kernel T: transpose W5 h-block into ws (for k2_y row-dots) ----------------
__global__ __launch_bounds__(256) void kT_tr(const float* __restrict__ W5, float* __restrict__ ws)
{
  int idx = blockIdx.x * 256 + threadIdx.x;   // 0..16383
  int j = idx >> 7, k = idx & 127;
  ws[OFF_WT5 + j * DK + k] = W5[(128 + k) * DK + j];
}

// ---------------- kernel 1: carry-independent per-step preactivations ----------------
__global__ __launch_bounds__(512) void k1_pre(
    const int* __restrict__ e_data, const int* __restrict__ it_data,
    const float* __restrict__ it_E, const float* __restrict__ e_E,
    const float* __restrict__ W2, const float* __restrict__ b2,
    const float* __restrict__ W3, const float* __restrict__ b3,
    const float* __restrict__ W4, const float* __restrict__ b4,
    const float* __restrict__ W5, const float* __restrict__ b5,
    float* __restrict__ ws)
{
  __shared__ float als[33][128];
  __shared__ float its[32][128];
  __shared__ float ens[32][128];
  int b = blockIdx.x >> 2, sh = blockIdx.x & 3, s0 = sh * 32;
  for (int idx = threadIdx.x; idx < 33 * 128; idx += 512) {
    int r = idx >> 7, j = idx & 127;
    int srow = s0 - 1 + r;
    als[r][j] = (srow >= 0) ? ws[OFF_AL + (b * S + srow) * DK + j] : 0.f;
  }
  for (int idx = threadIdx.x; idx < 32 * 128; idx += 512) {
    int r = idx >> 7, j = idx & 127;
    int itv = it_data[b * S + s0 + r];
    its[r][j] = it_E[itv * DK + j];
    int sg = s0 + r + 1; if (sg > 127) sg = 127;
    int ev = e_data[b * S + sg];
    ens[r][j] = e_E[ev * DK + j];
  }
  __syncthreads();
  int j = threadIdx.x & 127, sq = threadIdx.x >> 7;
  float p2[8], p3[8], pS[8], pY[8];
#pragma unroll
  for (int u = 0; u < 8; ++u) { p2[u] = b2[j]; p3[u] = b3[j]; pS[u] = b4[j]; pY[u] = b5[j]; }
  for (int k = 0; k < 128; ++k) {
    float w2 = W2[k * DK + j], w3 = W3[k * DK + j];
#pragma unroll
    for (int u = 0; u < 8; ++u) { float v = als[sq * 8 + u][k]; p2[u] += v * w2; p3[u] += v * w3; }
  }
  for (int k = 0; k < 128; ++k) {
    float w2 = W2[(128 + k) * DK + j], w3 = W3[(128 + k) * DK + j], w4 = W4[(256 + k) * DK + j];
#pragma unroll
    for (int u = 0; u < 8; ++u) { float v = its[sq * 8 + u][k]; p2[u] += v * w2; p3[u] += v * w3; pS[u] += v * w4; }
  }
  for (int k = 0; k < 128; ++k) {
    float w2 = W2[(256 + k) * DK + j], w3 = W3[(256 + k) * DK + j];
#pragma unroll
    for (int u = 0; u < 8; ++u) { float v = als[sq * 8 + u + 1][k]; p2[u] += v * w2; p3[u] += v * w3; }
  }
  for (int k = 0; k < 128; ++k) {
    float w5 = W5[k * DK + j];
#pragma unroll
    for (int u = 0; u < 8; ++u) pY[u] += ens[sq * 8 + u][k] * w5;
  }
#pragma unroll
  for (int u = 0; u < 8; ++u) {
    int s = s0 + sq * 8 + u;
    if (s < 127) {
      int o = (b * 127 + s) * DK + j;
      ws[OFF_P2 + o] = p2[u]; ws[OFF_P3 + o] = p3[u];
      ws[OFF_PS + o] = pS[u]; ws[OFF_PY + o] = pY[u];
    }
  }
}

// ---------------- main recurrent kernel: 4 barriers/step ----------------
// 1 block/batch row, 512 thr. Phases:
//  P1 [refill(1/4) + MFMA->acc + fused A-dot/LG via 4-lane DPP butterfly] b1
//  P3 [B-dot -> sbcpT] b2
//  X  [sbc sum + gamma + h-update + pack + ht partials] b3
//  R  [htld reduce + HTST] b4
// A-dot decomposition: jA=tid>>2, am=(tid>>1)&1, akh=tid&1; butterfly gives all
// lanes v2+v3 in-register -> LG inline (no P2 phase, no ap round-trip).
__global__ __launch_bounds__(512, 2) void kmain(
    const int* __restrict__ e_data, const float* __restrict__ qmat,
    const float* __restrict__ W2, const float* __restrict__ W3,
    const float* __restrict__ W4, const float* __restrict__ h0,
    float* __restrict__ ws)
{
  __shared__ char     hsb[65536];        // h bf16 [c][k] XOR-swizzled
  __shared__ uint32_t W4Lp[64][128];     // W4[128:256] bf16 pairs [k/2][j]          (32KB)
  __shared__ u32x4    W4B[4][8][64];     // W4[0:128] MFMA B-frags [jb][kk][lane]    (32KB)
  __shared__ float    QST[2][4][256];    // staged q rows                            (8KB)
  __shared__ float    PST[2][3][4][128]; // staged preacts (r2,r3,rS)                (12KB)
  __shared__ float    HTST[4][128];      // h_tilde history for batched flush        (2KB)
  __shared__ float    sbcpT[128][4];     // B-dot partials, transposed               (2KB)
  __shared__ float    LGs[128];
  __shared__ float    htld[128];
  __shared__ float    htp[4][128];

  const int b = blockIdx.x;
  const int tid = threadIdx.x;
  const int lane = tid & 63, wv = tid >> 6;
  const int cg = wv >> 1, jg = wv & 1;
  const int lo = lane & 31, hi = lane >> 5;
  const int j = tid & 127;
  const int jA = tid >> 2, am = (tid >> 1) & 1, akh = tid & 1;  // fused A-dot/LG slice
  const int kq = tid >> 7;                                      // B-dot k-quarter

  // ---- persistent registers: Aw (32) + hm (64) ----
  uint32_t Aw[32];
  {
    const float* Wm = am ? W3 : W2;
#pragma unroll
    for (int i = 0; i < 32; ++i) {
      float w0 = Wm[(384 + akh * 64 + 2 * i) * DK + jA];
      float w1 = Wm[(384 + akh * 64 + 2 * i + 1) * DK + jA];
      Aw[i] = pkbf(w0, w1);
    }
  }
  float hm[2][2][16];
#pragma unroll
  for (int ci = 0; ci < 2; ++ci)
#pragma unroll
    for (int ji = 0; ji < 2; ++ji)
#pragma unroll
      for (int r = 0; r < 16; ++r) {
        int row = (r & 3) + 8 * (r >> 2) + 4 * hi;
        hm[ci][ji][r] = h0[(cg * 64 + ci * 32 + row) * DK + jg * 64 + ji * 32 + lo];
      }

  // ---- prologue LDS fills ----
#pragma unroll
  for (int it = 0; it < 16; ++it) {                // W4Lp
    int idx = tid + it * 512, kp = idx >> 7, jj = idx & 127;
    W4Lp[kp][jj] = pkbf(W4[(128 + 2 * kp) * DK + jj], W4[(128 + 2 * kp + 1) * DK + jj]);
  }
  {
    uint32_t* w4b = (uint32_t*)&W4B[0][0][0];
#pragma unroll
    for (int it = 0; it < 16; ++it) {              // W4B frag layout of W4 rows 0..127
      int idx = tid + it * 512;                    // 0..8191
      int w = idx & 3, l = (idx >> 2) & 63, kk = (idx >> 8) & 7, jb = idx >> 11;
      int llo = l & 31, lhi = l >> 5;
      int row = kk * 16 + lhi * 8 + 2 * w, col = jb * 32 + llo;
      w4b[idx] = pkbf(W4[row * DK + col], W4[(row + 1) * DK + col]);
    }
  }
#pragma unroll
  for (int it = 0; it < 2; ++it) {                 // QST bank0 = q[0..3]
    int idx = tid + it * 512, rr = idx >> 8, cc = idx & 255;
    QST[0][rr][cc] = qmat[e_data[b * S + rr] * NC + cc];
  }
#pragma unroll
  for (int it = 0; it < 3; ++it) {                 // PST bank0 = preacts[0..3]
    int idx = tid + it * 512, mm = idx >> 9, rr = (idx >> 7) & 3, jj = idx & 127;
    int off = (mm == 0) ? OFF_P2 : (mm == 1) ? OFF_P3 : OFF_PS;
    PST[0][mm][rr][jj] = ws[off + (b * 127 + rr) * DK + jj];
  }
#pragma unroll
  for (int ci = 0; ci < 2; ++ci)                   // pack h0 into hsb
#pragma unroll
    for (int ji = 0; ji < 2; ++ji)
#pragma unroll
      for (int r = 0; r < 16; ++r) {
        int row = (r & 3) + 8 * (r >> 2) + 4 * hi;
        int c = cg * 64 + ci * 32 + row;
        int jb = (jg * 64 + ji * 32 + lo) * 2;
        *(uint16_t*)(hsb + c * 256 + (jb ^ ((c & 15) << 4))) = (uint16_t)pkbf(hm[ci][ji][r], 0.f);
      }
  __syncthreads();

  // ---- h_tilde_init ----
  {
    float ht0 = 0.f, ht1 = 0.f;
#pragma unroll
    for (int ci = 0; ci < 2; ++ci)
#pragma unroll
      for (int r = 0; r < 16; ++r) {
        int row = (r & 3) + 8 * (r >> 2) + 4 * hi;
        float qv = QST[0][0][cg * 64 + ci * 32 + row];
        ht0 += qv * hm[ci][0][r];
        ht1 += qv * hm[ci][1][r];
      }
    ht0 += __shfl_xor(ht0, 32);
    ht1 += __shfl_xor(ht1, 32);
    if (hi == 0) { htp[cg][jg * 64 + lo] = ht0; htp[cg][jg * 64 + 32 + lo] = ht1; }
  }
  __syncthreads();
  if (tid < 128) htld[tid] = htp[0][tid] + htp[1][tid] + htp[2][tid] + htp[3][tid];
  __syncthreads();

#pragma unroll 1
  for (int s = 0; s < S - 1; ++s) {
    const int u = s & 3, bank = (s >> 2) & 1;
    const bool refill = (u == 0);

    // ===== P1: refill-issue + MFMA + fused A-dot/LG + refill-commit =====
    float qld[2], pld[3];
    if (refill) {
      if (s > 0) {                                 // flush prev 4 steps' h_tilde
        int rr = tid >> 7, jj = tid & 127;
        ws[OFF_HT + (b * 127 + (s - 4) + rr) * DK + jj] = HTST[rr][jj];
      }
#pragma unroll
      for (int it = 0; it < 2; ++it) {             // q rows for steps s+4..s+7
        int idx = tid + it * 512, rr = idx >> 8, cc = idx & 255;
        qld[it] = qmat[e_data[b * S + min(s + 4 + rr, S - 1)] * NC + cc];
      }
#pragma unroll
      for (int it = 0; it < 3; ++it) {             // preacts for steps s+4..s+7
        int idx = tid + it * 512, mm = idx >> 9, rr = (idx >> 7) & 3, jj = idx & 127;
        int off = (mm == 0) ? OFF_P2 : (mm == 1) ? OFF_P3 : OFF_PS;
        pld[it] = ws[off + (b * 127 + min(s + 4 + rr, S - 2)) * DK + jj];
      }
    }

    // MFMA: pre[c,j] = h_bf16 @ W4h
    f32x16 acc[2][2];
#pragma unroll
    for (int ci = 0; ci < 2; ++ci)
#pragma unroll
      for (int r = 0; r < 16; ++r) { acc[ci][0][r] = 0.f; acc[ci][1][r] = 0.f; }
#pragma unroll
    for (int kk = 0; kk < 8; ++kk) {
      u32x4 bf0 = W4B[jg * 2 + 0][kk][lane];
      u32x4 bf1 = W4B[jg * 2 + 1][kk][lane];
#pragma unroll
      for (int ci = 0; ci < 2; ++ci) {
        int c = cg * 64 + ci * 32 + lo;
        bf16x8 af = __builtin_bit_cast(bf16x8,
            *(const u32x4*)(hsb + c * 256 + ((kk * 32 + hi * 16) ^ ((c & 15) << 4))));
        acc[ci][0] = __builtin_amdgcn_mfma_f32_32x32x16_bf16(af, __builtin_bit_cast(bf16x8, bf0), acc[ci][0], 0, 0, 0);
        acc[ci][1] = __builtin_amdgcn_mfma_f32_32x32x16_bf16(af, __builtin_bit_cast(bf16x8, bf1), acc[ci][1], 0, 0, 0);
      }
    }

    // fused A-dot + LG: partial 64-k dot, DPP butterfly, inline sigmoid
    {
      float p = 0.f;
#pragma unroll
      for (int t = 0; t < 16; ++t) {
        float4 h4 = *(const float4*)&htld[akh * 64 + 4 * t];
        uint32_t w0 = Aw[2 * t], w1 = Aw[2 * t + 1];
        p += bflo(w0) * h4.x + bfhi(w0) * h4.y + bflo(w1) * h4.z + bfhi(w1) * h4.w;
      }
      p += __shfl_xor(p, 1);                       // kh-sum
      float po = __shfl_xor(p, 2);                 // m-exchange
      float v2 = am ? po : p;
      float v3 = am ? p : po;
      v2 += PST[bank][0][u][jA];
      v3 += PST[bank][1][u][jA];
      float lg = sigm(v3) * sigm(2.f * v2);        // sigmoid(v3)*(tanh(v2)+1)/2
      if ((tid & 3) == 0) LGs[jA] = lg;
    }

    if (refill) {                                  // commit staged data
#pragma unroll
      for (int it = 0; it < 2; ++it) {
        int idx = tid + it * 512, rr = idx >> 8, cc = idx & 255;
        QST[bank ^ 1][rr][cc] = qld[it];
      }
#pragma unroll
      for (int it = 0; it < 3; ++it) {
        int idx = tid + it * 512, mm = idx >> 9, rr = (idx >> 7) & 3, jj = idx & 127;
        PST[bank ^ 1][mm][rr][jj] = pld[it];
      }
    }
    __syncthreads(); // b1

    // ===== P3: B-dot partials (sbc = rS + W4L . LG), transposed store =====
    {
      float pB = 0.f;
#pragma unroll
      for (int t = 0; t < 8; ++t) {
        float4 g4 = *(const float4*)&LGs[kq * 32 + 4 * t];
        uint32_t w0 = W4Lp[kq * 16 + 2 * t][j], w1 = W4Lp[kq * 16 + 2 * t + 1][j];
        pB += bflo(w0) * g4.x + bfhi(w0) * g4.y + bflo(w1) * g4.z + bfhi(w1) * g4.w;
      }
      sbcpT[j][kq] = pB;
    }
    __syncthreads(); // b2

    // ===== X: gamma / h-update / pack =====
    {
      const float* qc = &QST[bank][u][0];
      const float* qn = (u < 3) ? &QST[bank][u + 1][0] : &QST[bank ^ 1][0][0];
      int j0 = jg * 64 + lo, j1 = j0 + 32;
      float4 s40 = *(const float4*)&sbcpT[j0][0];
      float4 s41 = *(const float4*)&sbcpT[j1][0];
      float sb0 = PST[bank][2][u][j0] + s40.x + s40.y + s40.z + s40.w;
      float sb1 = PST[bank][2][u][j1] + s41.x + s41.y + s41.z + s41.w;
      float sn0 = sb0 * NLOG2E, sn1 = sb1 * NLOG2E;
      float lg0 = LGs[j0], lg1 = LGs[j1];
      float ht0 = 0.f, ht1 = 0.f;
#pragma unroll
      for (int ci = 0; ci < 2; ++ci) {
#pragma unroll
        for (int q = 0; q < 4; ++q) {              // r-quad: c = base..base+3 consecutive
          int cbase = cg * 64 + ci * 32 + 8 * q + 4 * hi;
          float4 qe4 = *(const float4*)&qc[cbase];
          float4 qn4 = *(const float4*)&qn[cbase];
#pragma unroll
          for (int rr = 0; rr < 4; ++rr) {
            int r = 4 * q + rr;
            float qe = (rr == 0) ? qe4.x : (rr == 1) ? qe4.y : (rr == 2) ? qe4.z : qe4.w;
            float qq = (rr == 0) ? qn4.x : (rr == 1) ? qn4.y : (rr == 2) ? qn4.z : qn4.w;
            int c = cbase + rr;
            float g0 = v_rcp(1.0f + v_exp2(fmaf(acc[ci][0][r], NLOG2E, sn0)));
            float hn0 = fmaf(g0, hm[ci][0][r], qe * lg0);
            hm[ci][0][r] = hn0; ht0 = fmaf(qq, hn0, ht0);
            float g1 = v_rcp(1.0f + v_exp2(fmaf(acc[ci][1][r], NLOG2E, sn1)));
            float hn1 = fmaf(g1, hm[ci][1][r], qe * lg1);
            hm[ci][1][r] = hn1; ht1 = fmaf(qq, hn1, ht1);
            int base = c * 256, swz = (c & 15) << 4;
            *(uint16_t*)(hsb + base + ((j0 * 2) ^ swz)) = (uint16_t)pkbf(hn0, 0.f);
            *(uint16_t*)(hsb + base + ((j1 * 2) ^ swz)) = (uint16_t)pkbf(hn1, 0.f);
          }
        }
      }
      ht0 += __shfl_xor(ht0, 32);
      ht1 += __shfl_xor(ht1, 32);
      if (hi == 0) { htp[cg][j0] = ht0; htp[cg][j1] = ht1; }
    }
    __syncthreads(); // b3

    // ===== R: h_tilde reduce =====
    if (tid < 128) {
      float v = htp[0][tid] + htp[1][tid] + htp[2][tid] + htp[3][tid];
      htld[tid] = v;
      HTST[u][tid] = v;
    }
    __syncthreads(); // b4
  }

  // final flush: steps 124..126 (HTST rows 0..2)
  if (tid < 3 * 128) {
    int rr = tid >> 7, jj = tid & 127;
    ws[OFF_HT + (b * 127 + 124 + rr) * DK + jj] = HTST[rr][jj];
  }
}

// ---------------- kernel 2: deferred y = mean_j sigmoid(preY + h_tilde @ W5h) ----------------
__global__ __launch_bounds__(128) void k2_y(const float* __restrict__ ws, float* __restrict__ out)
{
  __shared__ float hts[8][128];
  __shared__ float part[2][8];
  int b = blockIdx.x >> 4, ch = blockIdx.x & 15, s0 = ch * 8;
  int j = threadIdx.x;
#pragma unroll
  for (int u = 0; u < 8; ++u) {
    int s = s0 + u;
    hts[u][j] = (s < 127) ? ws[OFF_HT + (b * 127 + s) * DK + j] : 0.f;
  }
  __syncthreads();
  float acc[8];
#pragma unroll
  for (int u = 0; u < 8; ++u) {
    int s = s0 + u;
    acc[u] = (s < 127) ? ws[OFF_PY + (b * 127 + s) * DK + j] : 0.f;
  }
  const float4* w5 = (const float4*)(ws + OFF_WT5 + j * DK);
#pragma unroll 8
  for (int i = 0; i < 32; ++i) {
    float4 w = w5[i];
#pragma unroll
    for (int u = 0; u < 8; ++u) {
      float4 h4 = *(const float4*)&hts[u][4 * i];
      acc[u] += w.x * h4.x + w.y * h4.y + w.z * h4.z + w.w * h4.w;
    }
  }
#pragma unroll
  for (int u = 0; u < 8; ++u) {
    float v = sigm(acc[u]);
#pragma unroll
    for (int off = 32; off >= 1; off >>= 1) v += __shfl_xor(v, off);
    if ((j & 63) == 0) part[j >> 6][u] = v;
  }
  __syncthreads();
  if (j < 8) {
    int s = s0 + j;
    if (s < 127) out[b * S + s + 1] = (part[0][j] + part[1][j]) * (1.0f / 128.0f);
  }
  if (j == 0 && ch == 0) out[b * S] = 0.f;
}

extern "C" void kernel_launch(void* const* d_in, const int* in_sizes, int n_in,
                              void* d_out, int out_size, void* d_ws, size_t ws_size,
                              hipStream_t stream)
{
  (void)in_sizes; (void)n_in; (void)out_size; (void)ws_size;
  const int*   e_data  = (const int*)  d_in[0];
  const int*   at_data = (const int*)  d_in[1];
  const int*   it_data = (const int*)  d_in[2];
  const float* a_data  = (const float*)d_in[3];
  const float* qmat    = (const float*)d_in[4];
  const float* e_E     = (const float*)d_in[5];
  const float* at_E    = (const float*)d_in[6];
  const float* it_E    = (const float*)d_in[7];
  const float* W1 = (const float*)d_in[8];  const float* b1 = (const float*)d_in[9];
  const float* W2 = (const float*)d_in[10]; const float* b2 = (const float*)d_in[11];
  const float* W3 = (const float*)d_in[12]; const float* b3 = (const float*)d_in[13];
  const float* W4 = (const float*)d_in[14]; const float* b4 = (const float*)d_in[15];
  const float* W5 = (const float*)d_in[16]; const float* b5 = (const float*)d_in[17];
  const float* h0 = (const float*)d_in[18];
  float* ws  = (float*)d_ws;
  float* out = (float*)d_out;

  k0_al <<<128, 512, 0, stream>>>(e_data, at_data, a_data, e_E, at_E, W1, b1, ws);
  kT_tr <<<64, 256, 0, stream>>>(W5, ws);
  k1_pre<<<128, 512, 0, stream>>>(e_data, it_data, it_E, e_E, W2, b2, W3, b3, W4, b4, W5, b5, ws);
  kmain <<<32, 512, 0, stream>>>(e_data, qmat, W2, W3, W4, h0, ws);
  k2_y  <<<512, 128, 0, stream>>>(ws, out);
}

// Round 7
// 603.172 us; speedup vs baseline: 4.2841x; 1.9507x over previous
//
#include <hip/hip_runtime.h>
#include <stdint.h>

#define S   128
#define NB  32
#define NC  256
#define DK  128
#define NSL 4

typedef __bf16 bf16x8 __attribute__((ext_vector_type(8)));
typedef float  f32x16 __attribute__((ext_vector_type(16)));
typedef unsigned int u32x4 __attribute__((ext_vector_type(4)));
static_assert(sizeof(bf16x8) == 16, "bf16x8 size");
static_assert(sizeof(u32x4) == 16, "u32x4 size");

// d_ws layout (float offsets).
#define OFF_AL   0            // [32][128][128] AL; later OFF_HT (reduced h_tilde) reuse
#define OFF_HT   OFF_AL
#define OFF_P2   524288
#define OFF_P3   1044480
#define OFF_PS   1564672
#define OFF_PY   2084864
#define OFF_WT5  2654208
#define OFF_CM   2670592      // comm partials [32 b][2 parity][4 slice][128]
#define OFF_FG   2703360      // flags [32 b][4 slice] u32  (memset to 0 each launch)

__device__ __forceinline__ float v_exp2(float x){ float r; asm("v_exp_f32 %0, %1" : "=v"(r) : "v"(x)); return r; }
__device__ __forceinline__ float v_rcp (float x){ float r; asm("v_rcp_f32 %0, %1" : "=v"(r) : "v"(x)); return r; }
__device__ __forceinline__ float sigm(float x){ return v_rcp(1.0f + v_exp2(x * -1.4426950408889634f)); }
__device__ __forceinline__ uint32_t pkbf(float lo, float hi){
  uint32_t r; asm("v_cvt_pk_bf16_f32 %0, %1, %2" : "=v"(r) : "v"(lo), "v"(hi)); return r;
}
__device__ __forceinline__ float bflo(uint32_t w){ return __builtin_bit_cast(float, w << 16); }
__device__ __forceinline__ float bfhi(uint32_t w){ return __builtin_bit_cast(float, w & 0xffff0000u); }
#define NLOG2E (-1.4426950408889634f)

// ---------------- kernel 0: AL = concat(e_emb, at_emb, a*ones50) @ W1 + b1 ----------------
__global__ __launch_bounds__(512) void k0_al(
    const int* __restrict__ e_data, const int* __restrict__ at_data,
    const float* __restrict__ a_data, const float* __restrict__ e_E,
    const float* __restrict__ at_E, const float* __restrict__ W1,
    const float* __restrict__ b1, float* __restrict__ ws)
{
  __shared__ float ein[32][128];
  __shared__ float atin[32][128];
  int b = blockIdx.x >> 2, q4 = blockIdx.x & 3, t0 = q4 * 32;
  for (int idx = threadIdx.x; idx < 32 * 128; idx += 512) {
    int r = idx >> 7, j = idx & 127;
    int ev  = e_data [b * S + t0 + r];
    int atv = at_data[b * S + t0 + r];
    ein [r][j] = e_E [ev  * DK + j];
    atin[r][j] = at_E[atv * DK + j];
  }
  __syncthreads();
  int j = threadIdx.x & 127, tq = threadIdx.x >> 7;
  float w1s = 0.f;
  for (int d = 0; d < 50; ++d) w1s += W1[(256 + d) * DK + j];
  float acc[8];
#pragma unroll
  for (int u = 0; u < 8; ++u) {
    int t = t0 + tq * 8 + u;
    acc[u] = b1[j] + a_data[b * S + t] * w1s;
  }
  for (int k = 0; k < 128; ++k) {
    float w = W1[k * DK + j];
#pragma unroll
    for (int u = 0; u < 8; ++u) acc[u] += ein[tq * 8 + u][k] * w;
  }
  for (int k = 0; k < 128; ++k) {
    float w = W1[(128 + k) * DK + j];
#pragma unroll
    for (int u = 0; u < 8; ++u) acc[u] += atin[tq * 8 + u][k] * w;
  }
#pragma unroll
  for (int u = 0; u < 8; ++u)
    ws[OFF_AL + (b * S + t0 + tq * 8 + u) * DK + j] = acc[u];
}

// ---------------- kernel T: transpose W5 h-block into ws ----------------
__global__ __launch_bounds__(256) void kT_tr(const float* __restrict__ W5, float* __restrict__ ws)
{
  int idx = blockIdx.x * 256 + threadIdx.x;
  int j = idx >> 7, k = idx & 127;
  ws[OFF_WT5 + j * DK + k] = W5[(128 + k) * DK + j];
}

// ---------------- kernel 1: carry-independent per-step preactivations ----------------
__global__ __launch_bounds__(512) void k1_pre(
    const int* __restrict__ e_data, const int* __restrict__ it_data,
    const float* __restrict__ it_E, const float* __restrict__ e_E,
    const float* __restrict__ W2, const float* __restrict__ b2,
    const float* __restrict__ W3, const float* __restrict__ b3,
    const float* __restrict__ W4, const float* __restrict__ b4,
    const float* __restrict__ W5, const float* __restrict__ b5,
    float* __restrict__ ws)
{
  __shared__ float als[33][128];
  __shared__ float its[32][128];
  __shared__ float ens[32][128];
  int b = blockIdx.x >> 2, sh = blockIdx.x & 3, s0 = sh * 32;
  for (int idx = threadIdx.x; idx < 33 * 128; idx += 512) {
    int r = idx >> 7, j = idx & 127;
    int srow = s0 - 1 + r;
    als[r][j] = (srow >= 0) ? ws[OFF_AL + (b * S + srow) * DK + j] : 0.f;
  }
  for (int idx = threadIdx.x; idx < 32 * 128; idx += 512) {
    int r = idx >> 7, j = idx & 127;
    int itv = it_data[b * S + s0 + r];
    its[r][j] = it_E[itv * DK + j];
    int sg = s0 + r + 1; if (sg > 127) sg = 127;
    int ev = e_data[b * S + sg];
    ens[r][j] = e_E[ev * DK + j];
  }
  __syncthreads();
  int j = threadIdx.x & 127, sq = threadIdx.x >> 7;
  float p2[8], p3[8], pS[8], pY[8];
#pragma unroll
  for (int u = 0; u < 8; ++u) { p2[u] = b2[j]; p3[u] = b3[j]; pS[u] = b4[j]; pY[u] = b5[j]; }
  for (int k = 0; k < 128; ++k) {
    float w2 = W2[k * DK + j], w3 = W3[k * DK + j];
#pragma unroll
    for (int u = 0; u < 8; ++u) { float v = als[sq * 8 + u][k]; p2[u] += v * w2; p3[u] += v * w3; }
  }
  for (int k = 0; k < 128; ++k) {
    float w2 = W2[(128 + k) * DK + j], w3 = W3[(128 + k) * DK + j], w4 = W4[(256 + k) * DK + j];
#pragma unroll
    for (int u = 0; u < 8; ++u) { float v = its[sq * 8 + u][k]; p2[u] += v * w2; p3[u] += v * w3; pS[u] += v * w4; }
  }
  for (int k = 0; k < 128; ++k) {
    float w2 = W2[(256 + k) * DK + j], w3 = W3[(256 + k) * DK + j];
#pragma unroll
    for (int u = 0; u < 8; ++u) { float v = als[sq * 8 + u + 1][k]; p2[u] += v * w2; p3[u] += v * w3; }
  }
  for (int k = 0; k < 128; ++k) {
    float w5 = W5[k * DK + j];
#pragma unroll
    for (int u = 0; u < 8; ++u) pY[u] += ens[sq * 8 + u][k] * w5;
  }
#pragma unroll
  for (int u = 0; u < 8; ++u) {
    int s = s0 + sq * 8 + u;
    if (s < 127) {
      int o = (b * 127 + s) * DK + j;
      ws[OFF_P2 + o] = p2[u]; ws[OFF_P3 + o] = p3[u];
      ws[OFF_PS + o] = pS[u]; ws[OFF_PY + o] = pY[u];
    }
  }
}

// ---------------- main recurrent kernel: 4 CUs per batch row (c-split) ----------------
// grid 128 = slice(0..3) x b(0..31); block owns c in [64*slice, 64*slice+64), 512 thr.
// wave (ct,jt) = (wv>>2, wv&3): c-tile 32, j-tile 32. hm = 16 f32 regs/thread.
// Per step: P1 [HT store + MFMA(8) + fused A-dot/LG] b1 | P3 [B-dot + htld=0] b2 |
// X [gamma/update/pack + partial h_tilde] b3 | R1 [partial->IC + prefetch] b4 |
// R2 [flag + spin on 4 partner flags] b5 | R3 [gather+LDS-add htld + commit] b6.
// Cross-CU protocol: relaxed-agent stores, syncthreads vmcnt-drain before flag,
// monotone seq flags (zeroed each launch by hipMemsetAsync), parity double-buffer.
__global__ __launch_bounds__(512, 2) void kmain(
    const int* __restrict__ e_data, const float* __restrict__ qmat,
    const float* __restrict__ W2, const float* __restrict__ W3,
    const float* __restrict__ W4, const float* __restrict__ h0,
    float* ws)
{
  __shared__ char     hsb[16384];        // h slice bf16 [64 c][128 k] XOR-swizzled
  __shared__ uint32_t W4Lp[64][128];     // W4[128:256] bf16 pairs                (32KB)
  __shared__ u32x4    W4B[4][8][64];     // W4[0:128] MFMA B-frags                (32KB)
  __shared__ float    qring[2][64];      // q rows (own slice), 2-step ring
  __shared__ float    PST[2][3][128];    // preacts r2,r3,rS, 2-step ring
  __shared__ float    LGs[128];
  __shared__ float    htld[128];
  __shared__ float    sbcp[4][128];
  __shared__ float    htp[2][128];

  const int bx = blockIdx.x;
  const int b = bx & 31, slice = bx >> 5;
  const int tid = threadIdx.x;
  const int lane = tid & 63, wv = tid >> 6;
  const int ct = wv >> 2, jt = wv & 3;
  const int lo = lane & 31, hi = lane >> 5;
  const int j = tid & 127;
  const int jA = tid >> 2, am = (tid >> 1) & 1, akh = tid & 1;
  const int kq = tid >> 7;
  const int jloc = jt * 32 + lo;

  float* cm = ws + OFF_CM + b * (2 * NSL * 128);     // [parity][slice][128]
  uint32_t* fg = (uint32_t*)(ws + OFF_FG) + b * NSL; // [slice]

  // ---- persistent registers: Aw (32) + hm (16) ----
  uint32_t Aw[32];
  {
    const float* Wm = am ? W3 : W2;
#pragma unroll
    for (int i = 0; i < 32; ++i) {
      float w0 = Wm[(384 + akh * 64 + 2 * i) * DK + jA];
      float w1 = Wm[(384 + akh * 64 + 2 * i + 1) * DK + jA];
      Aw[i] = pkbf(w0, w1);
    }
  }
  float hm[16];
#pragma unroll
  for (int r = 0; r < 16; ++r) {
    int cl = ct * 32 + (r & 3) + 8 * (r >> 2) + 4 * hi;
    hm[r] = h0[(slice * 64 + cl) * DK + jloc];
  }

  // ---- prologue LDS fills ----
#pragma unroll
  for (int it = 0; it < 16; ++it) {
    int idx = tid + it * 512, kp = idx >> 7, jj = idx & 127;
    W4Lp[kp][jj] = pkbf(W4[(128 + 2 * kp) * DK + jj], W4[(128 + 2 * kp + 1) * DK + jj]);
  }
  {
    uint32_t* w4b = (uint32_t*)&W4B[0][0][0];
#pragma unroll
    for (int it = 0; it < 16; ++it) {
      int idx = tid + it * 512;
      int w = idx & 3, l = (idx >> 2) & 63, kk = (idx >> 8) & 7, jb = idx >> 11;
      int llo = l & 31, lhi = l >> 5;
      int row = kk * 16 + lhi * 8 + 2 * w, col = jb * 32 + llo;
      w4b[idx] = pkbf(W4[row * DK + col], W4[(row + 1) * DK + col]);
    }
  }
  if (tid < 64) {
    qring[0][tid] = qmat[e_data[b * S + 0] * NC + slice * 64 + tid];
    qring[1][tid] = qmat[e_data[b * S + 1] * NC + slice * 64 + tid];
  }
  if (tid < 384) {
    int mm = tid >> 7, jj = tid & 127;
    int off = (mm == 0) ? OFF_P2 : (mm == 1) ? OFF_P3 : OFF_PS;
    PST[0][mm][jj] = ws[off + (b * 127 + 0) * DK + jj];
  }
#pragma unroll
  for (int r = 0; r < 16; ++r) {                 // pack h0 slice into hsb
    int cl = ct * 32 + (r & 3) + 8 * (r >> 2) + 4 * hi;
    *(uint16_t*)(hsb + cl * 256 + ((jloc * 2) ^ ((cl & 15) << 4))) = (uint16_t)pkbf(hm[r], 0.f);
  }
  if (tid < 128) htld[tid] = 0.f;
  __syncthreads();

  // ---- prologue: partial(0) = q(0) . h0 slice, exchange, htld(0) ----
  {
    float ht = 0.f;
#pragma unroll
    for (int r = 0; r < 16; ++r) {
      int cl = ct * 32 + (r & 3) + 8 * (r >> 2) + 4 * hi;
      ht += qring[0][cl] * hm[r];
    }
    ht += __shfl_xor(ht, 32);
    if (hi == 0) htp[ct][jloc] = ht;
  }
  __syncthreads();
  if (tid < 128) {
    float p = htp[0][tid] + htp[1][tid];
    __hip_atomic_store(&cm[0 * (NSL * 128) + slice * 128 + tid], p,
                       __ATOMIC_RELAXED, __HIP_MEMORY_SCOPE_AGENT);
  }
  __syncthreads();                                   // drains partial stores (vmcnt 0)
  if (tid == 0)
    __hip_atomic_store(&fg[slice], 1u, __ATOMIC_RELAXED, __HIP_MEMORY_SCOPE_AGENT);
  if (wv == 0) {
    for (;;) {
      uint32_t f = __hip_atomic_load(&fg[lane & 3], __ATOMIC_RELAXED, __HIP_MEMORY_SCOPE_AGENT);
      if (__all(f >= 1u)) break;
      __builtin_amdgcn_s_sleep(2);
    }
  }
  __syncthreads();
  {
    int sl = tid >> 7, jj = tid & 127;
    float v = __hip_atomic_load(&cm[0 * (NSL * 128) + sl * 128 + jj],
                                __ATOMIC_RELAXED, __HIP_MEMORY_SCOPE_AGENT);
    atomicAdd(&htld[jj], v);
  }
  __syncthreads();

#pragma unroll 1
  for (int s = 0; s < S - 1; ++s) {
    const int par = s & 1, parn = (s + 1) & 1;

    // ===== P1: HT store (slice 0) + MFMA + fused A-dot/LG =====
    if (slice == 0 && s > 0 && tid < 128)
      ws[OFF_HT + (b * 127 + (s - 1)) * DK + tid] = htld[tid];

    f32x16 acc;
#pragma unroll
    for (int r = 0; r < 16; ++r) acc[r] = 0.f;
#pragma unroll
    for (int kk = 0; kk < 8; ++kk) {
      u32x4 bfr = W4B[jt][kk][lane];
      int cl = ct * 32 + lo;
      bf16x8 af = __builtin_bit_cast(bf16x8,
          *(const u32x4*)(hsb + cl * 256 + ((kk * 32 + hi * 16) ^ ((cl & 15) << 4))));
      acc = __builtin_amdgcn_mfma_f32_32x32x16_bf16(af, __builtin_bit_cast(bf16x8, bfr), acc, 0, 0, 0);
    }
    {
      float p = 0.f;
#pragma unroll
      for (int t = 0; t < 16; ++t) {
        float4 h4 = *(const float4*)&htld[akh * 64 + 4 * t];
        uint32_t w0 = Aw[2 * t], w1 = Aw[2 * t + 1];
        p += bflo(w0) * h4.x + bfhi(w0) * h4.y + bflo(w1) * h4.z + bfhi(w1) * h4.w;
      }
      p += __shfl_xor(p, 1);
      float po = __shfl_xor(p, 2);
      float v2 = am ? po : p;
      float v3 = am ? p : po;
      v2 += PST[par][0][jA];
      v3 += PST[par][1][jA];
      float lg = sigm(v3) * sigm(2.f * v2);
      if ((tid & 3) == 0) LGs[jA] = lg;
    }
    __syncthreads(); // b1

    // ===== P3: B-dot + htld zero =====
    {
      float pB = 0.f;
#pragma unroll
      for (int t = 0; t < 8; ++t) {
        float4 g4 = *(const float4*)&LGs[kq * 32 + 4 * t];
        uint32_t w0 = W4Lp[kq * 16 + 2 * t][j], w1 = W4Lp[kq * 16 + 2 * t + 1][j];
        pB += bflo(w0) * g4.x + bfhi(w0) * g4.y + bflo(w1) * g4.z + bfhi(w1) * g4.w;
      }
      sbcp[kq][j] = pB;
    }
    if (tid < 128) htld[tid] = 0.f;
    __syncthreads(); // b2

    // ===== X: gamma / h-update / pack + partial h_tilde =====
    {
      float sb = PST[par][2][jloc] + sbcp[0][jloc] + sbcp[1][jloc] + sbcp[2][jloc] + sbcp[3][jloc];
      float sn = sb * NLOG2E;
      float lgj = LGs[jloc];
      float ht = 0.f;
#pragma unroll
      for (int q4 = 0; q4 < 4; ++q4) {
        int cbase = ct * 32 + 8 * q4 + 4 * hi;
        float4 qe4 = *(const float4*)&qring[par][cbase];
        float4 qn4 = *(const float4*)&qring[parn][cbase];
#pragma unroll
        for (int rr = 0; rr < 4; ++rr) {
          int r = 4 * q4 + rr;
          float qe = (rr == 0) ? qe4.x : (rr == 1) ? qe4.y : (rr == 2) ? qe4.z : qe4.w;
          float qq = (rr == 0) ? qn4.x : (rr == 1) ? qn4.y : (rr == 2) ? qn4.z : qn4.w;
          int cl = cbase + rr;
          float g = v_rcp(1.0f + v_exp2(fmaf(acc[r], NLOG2E, sn)));
          float hn = fmaf(g, hm[r], qe * lgj);
          hm[r] = hn; ht = fmaf(qq, hn, ht);
          *(uint16_t*)(hsb + cl * 256 + ((jloc * 2) ^ ((cl & 15) << 4))) = (uint16_t)pkbf(hn, 0.f);
        }
      }
      ht += __shfl_xor(ht, 32);
      if (hi == 0) htp[ct][jloc] = ht;
    }
    __syncthreads(); // b3

    // ===== R1: partial -> IC + prefetch issue =====
    float pfq = 0.f, pfp = 0.f;
    if (tid < 64)
      pfq = qmat[e_data[b * S + min(s + 2, S - 1)] * NC + slice * 64 + tid];
    if (tid < 384) {
      int mm = tid >> 7, jj = tid & 127;
      int off = (mm == 0) ? OFF_P2 : (mm == 1) ? OFF_P3 : OFF_PS;
      pfp = ws[off + (b * 127 + min(s + 1, 126)) * DK + jj];
    }
    if (tid < 128) {
      float p = htp[0][tid] + htp[1][tid];
      __hip_atomic_store(&cm[parn * (NSL * 128) + slice * 128 + tid], p,
                         __ATOMIC_RELAXED, __HIP_MEMORY_SCOPE_AGENT);
    }
    __syncthreads(); // b4 (vmcnt drain: partial stores complete before flag)

    // ===== R2: flag + spin =====
    if (tid == 0)
      __hip_atomic_store(&fg[slice], (uint32_t)(s + 2), __ATOMIC_RELAXED, __HIP_MEMORY_SCOPE_AGENT);
    if (wv == 0) {
      uint32_t tgt = (uint32_t)(s + 2);
      for (;;) {
        uint32_t f = __hip_atomic_load(&fg[lane & 3], __ATOMIC_RELAXED, __HIP_MEMORY_SCOPE_AGENT);
        if (__all(f >= tgt)) break;
        __builtin_amdgcn_s_sleep(2);
      }
    }
    __syncthreads(); // b5

    // ===== R3: gather + commit prefetch =====
    {
      int sl = tid >> 7, jj = tid & 127;
      float v = __hip_atomic_load(&cm[parn * (NSL * 128) + sl * 128 + jj],
                                  __ATOMIC_RELAXED, __HIP_MEMORY_SCOPE_AGENT);
      atomicAdd(&htld[jj], v);
    }
    if (tid < 64) qring[par][tid] = pfq;           // q(s+2); q(s) dead
    if (tid < 384) {
      int mm = tid >> 7, jj = tid & 127;
      PST[parn][mm][jj] = pfp;                     // pre(s+1)
    }
    __syncthreads(); // b6
  }

  // epilogue: HT row 126 = h_tilde(127)
  if (slice == 0 && tid < 128)
    ws[OFF_HT + (b * 127 + 126) * DK + tid] = htld[tid];
}

// ---------------- kernel 2: deferred y = mean_j sigmoid(preY + h_tilde @ W5h) ----------------
__global__ __launch_bounds__(128) void k2_y(const float* __restrict__ ws, float* __restrict__ out)
{
  __shared__ float hts[8][128];
  __shared__ float part[2][8];
  int b = blockIdx.x >> 4, ch = blockIdx.x & 15, s0 = ch * 8;
  int j = threadIdx.x;
#pragma unroll
  for (int u = 0; u < 8; ++u) {
    int s = s0 + u;
    hts[u][j] = (s < 127) ? ws[OFF_HT + (b * 127 + s) * DK + j] : 0.f;
  }
  __syncthreads();
  float acc[8];
#pragma unroll
  for (int u = 0; u < 8; ++u) {
    int s = s0 + u;
    acc[u] = (s < 127) ? ws[OFF_PY + (b * 127 + s) * DK + j] : 0.f;
  }
  const float4* w5 = (const float4*)(ws + OFF_WT5 + j * DK);
#pragma unroll 8
  for (int i = 0; i < 32; ++i) {
    float4 w = w5[i];
#pragma unroll
    for (int u = 0; u < 8; ++u) {
      float4 h4 = *(const float4*)&hts[u][4 * i];
      acc[u] += w.x * h4.x + w.y * h4.y + w.z * h4.z + w.w * h4.w;
    }
  }
#pragma unroll
  for (int u = 0; u < 8; ++u) {
    float v = sigm(acc[u]);
#pragma unroll
    for (int off = 32; off >= 1; off >>= 1) v += __shfl_xor(v, off);
    if ((j & 63) == 0) part[j >> 6][u] = v;
  }
  __syncthreads();
  if (j < 8) {
    int s = s0 + j;
    if (s < 127) out[b * S + s + 1] = (part[0][j] + part[1][j]) * (1.0f / 128.0f);
  }
  if (j == 0 && ch == 0) out[b * S] = 0.f;
}

extern "C" void kernel_launch(void* const* d_in, const int* in_sizes, int n_in,
                              void* d_out, int out_size, void* d_ws, size_t ws_size,
                              hipStream_t stream)
{
  (void)in_sizes; (void)n_in; (void)out_size; (void)ws_size;
  const int*   e_data  = (const int*)  d_in[0];
  const int*   at_data = (const int*)  d_in[1];
  const int*   it_data = (const int*)  d_in[2];
  const float* a_data  = (const float*)d_in[3];
  const float* qmat    = (const float*)d_in[4];
  const float* e_E     = (const float*)d_in[5];
  const float* at_E    = (const float*)d_in[6];
  const float* it_E    = (const float*)d_in[7];
  const float* W1 = (const float*)d_in[8];  const float* b1 = (const float*)d_in[9];
  const float* W2 = (const float*)d_in[10]; const float* b2 = (const float*)d_in[11];
  const float* W3 = (const float*)d_in[12]; const float* b3 = (const float*)d_in[13];
  const float* W4 = (const float*)d_in[14]; const float* b4 = (const float*)d_in[15];
  const float* W5 = (const float*)d_in[16]; const float* b5 = (const float*)d_in[17];
  const float* h0 = (const float*)d_in[18];
  float* ws  = (float*)d_ws;
  float* out = (float*)d_out;

  // zero the cross-CU seq flags (graph-capture-safe, replay-safe)
  hipMemsetAsync((char*)d_ws + (size_t)OFF_FG * 4, 0, NB * NSL * 4, stream);

  k0_al <<<128, 512, 0, stream>>>(e_data, at_data, a_data, e_E, at_E, W1, b1, ws);
  kT_tr <<<64, 256, 0, stream>>>(W5, ws);
  k1_pre<<<128, 512, 0, stream>>>(e_data, it_data, it_E, e_E, W2, b2, W3, b3, W4, b4, W5, b5, ws);
  kmain <<<128, 512, 0, stream>>>(e_data, qmat, W2, W3, W4, h0, ws);
  k2_y  <<<512, 128, 0, stream>>>(ws, out);
}

// Round 8
// 578.699 us; speedup vs baseline: 4.4653x; 1.0423x over previous
//
#include <hip/hip_runtime.h>
#include <stdint.h>

#define S   128
#define NB  32
#define NC  256
#define DK  128
#define NSL 4

typedef __bf16 bf16x8 __attribute__((ext_vector_type(8)));
typedef float  f32x16 __attribute__((ext_vector_type(16)));
typedef unsigned int u32x4 __attribute__((ext_vector_type(4)));
static_assert(sizeof(bf16x8) == 16, "bf16x8 size");
static_assert(sizeof(u32x4) == 16, "u32x4 size");

// d_ws layout (float offsets).
#define OFF_AL   0            // [32][128][128] AL; later OFF_HT (reduced h_tilde) reuse
#define OFF_HT   OFF_AL
#define OFF_P2   524288
#define OFF_P3   1044480
#define OFF_PS   1564672
#define OFF_PY   2084864
#define OFF_WT5  2654208
#define OFF_CM   2670592      // comm partials [32 b][2 parity][4 slice][128]
#define OFF_FG   2703360      // flags [32 b][4 slice] u32  (memset to 0 each launch)

__device__ __forceinline__ float v_exp2(float x){ float r; asm("v_exp_f32 %0, %1" : "=v"(r) : "v"(x)); return r; }
__device__ __forceinline__ float v_rcp (float x){ float r; asm("v_rcp_f32 %0, %1" : "=v"(r) : "v"(x)); return r; }
__device__ __forceinline__ float sigm(float x){ return v_rcp(1.0f + v_exp2(x * -1.4426950408889634f)); }
__device__ __forceinline__ uint32_t pkbf(float lo, float hi){
  uint32_t r; asm("v_cvt_pk_bf16_f32 %0, %1, %2" : "=v"(r) : "v"(lo), "v"(hi)); return r;
}
__device__ __forceinline__ float bflo(uint32_t w){ return __builtin_bit_cast(float, w << 16); }
__device__ __forceinline__ float bfhi(uint32_t w){ return __builtin_bit_cast(float, w & 0xffff0000u); }
#define NLOG2E (-1.4426950408889634f)

// ---------------- kernel 0: AL = concat(e_emb, at_emb, a*ones50) @ W1 + b1 ----------------
__global__ __launch_bounds__(512) void k0_al(
    const int* __restrict__ e_data, const int* __restrict__ at_data,
    const float* __restrict__ a_data, const float* __restrict__ e_E,
    const float* __restrict__ at_E, const float* __restrict__ W1,
    const float* __restrict__ b1, float* __restrict__ ws)
{
  __shared__ float ein[32][128];
  __shared__ float atin[32][128];
  int b = blockIdx.x >> 2, q4 = blockIdx.x & 3, t0 = q4 * 32;
  for (int idx = threadIdx.x; idx < 32 * 128; idx += 512) {
    int r = idx >> 7, j = idx & 127;
    int ev  = e_data [b * S + t0 + r];
    int atv = at_data[b * S + t0 + r];
    ein [r][j] = e_E [ev  * DK + j];
    atin[r][j] = at_E[atv * DK + j];
  }
  __syncthreads();
  int j = threadIdx.x & 127, tq = threadIdx.x >> 7;
  float w1s = 0.f;
  for (int d = 0; d < 50; ++d) w1s += W1[(256 + d) * DK + j];
  float acc[8];
#pragma unroll
  for (int u = 0; u < 8; ++u) {
    int t = t0 + tq * 8 + u;
    acc[u] = b1[j] + a_data[b * S + t] * w1s;
  }
  for (int k = 0; k < 128; ++k) {
    float w = W1[k * DK + j];
#pragma unroll
    for (int u = 0; u < 8; ++u) acc[u] += ein[tq * 8 + u][k] * w;
  }
  for (int k = 0; k < 128; ++k) {
    float w = W1[(128 + k) * DK + j];
#pragma unroll
    for (int u = 0; u < 8; ++u) acc[u] += atin[tq * 8 + u][k] * w;
  }
#pragma unroll
  for (int u = 0; u < 8; ++u)
    ws[OFF_AL + (b * S + t0 + tq * 8 + u) * DK + j] = acc[u];
}

// ---------------- kernel T: transpose W5 h-block into ws ----------------
__global__ __launch_bounds__(256) void kT_tr(const float* __restrict__ W5, float* __restrict__ ws)
{
  int idx = blockIdx.x * 256 + threadIdx.x;
  int j = idx >> 7, k = idx & 127;
  ws[OFF_WT5 + j * DK + k] = W5[(128 + k) * DK + j];
}

// ---------------- kernel 1: carry-independent per-step preactivations ----------------
__global__ __launch_bounds__(512) void k1_pre(
    const int* __restrict__ e_data, const int* __restrict__ it_data,
    const float* __restrict__ it_E, const float* __restrict__ e_E,
    const float* __restrict__ W2, const float* __restrict__ b2,
    const float* __restrict__ W3, const float* __restrict__ b3,
    const float* __restrict__ W4, const float* __restrict__ b4,
    const float* __restrict__ W5, const float* __restrict__ b5,
    float* __restrict__ ws)
{
  __shared__ float als[33][128];
  __shared__ float its[32][128];
  __shared__ float ens[32][128];
  int b = blockIdx.x >> 2, sh = blockIdx.x & 3, s0 = sh * 32;
  for (int idx = threadIdx.x; idx < 33 * 128; idx += 512) {
    int r = idx >> 7, j = idx & 127;
    int srow = s0 - 1 + r;
    als[r][j] = (srow >= 0) ? ws[OFF_AL + (b * S + srow) * DK + j] : 0.f;
  }
  for (int idx = threadIdx.x; idx < 32 * 128; idx += 512) {
    int r = idx >> 7, j = idx & 127;
    int itv = it_data[b * S + s0 + r];
    its[r][j] = it_E[itv * DK + j];
    int sg = s0 + r + 1; if (sg > 127) sg = 127;
    int ev = e_data[b * S + sg];
    ens[r][j] = e_E[ev * DK + j];
  }
  __syncthreads();
  int j = threadIdx.x & 127, sq = threadIdx.x >> 7;
  float p2[8], p3[8], pS[8], pY[8];
#pragma unroll
  for (int u = 0; u < 8; ++u) { p2[u] = b2[j]; p3[u] = b3[j]; pS[u] = b4[j]; pY[u] = b5[j]; }
  for (int k = 0; k < 128; ++k) {
    float w2 = W2[k * DK + j], w3 = W3[k * DK + j];
#pragma unroll
    for (int u = 0; u < 8; ++u) { float v = als[sq * 8 + u][k]; p2[u] += v * w2; p3[u] += v * w3; }
  }
  for (int k = 0; k < 128; ++k) {
    float w2 = W2[(128 + k) * DK + j], w3 = W3[(128 + k) * DK + j], w4 = W4[(256 + k) * DK + j];
#pragma unroll
    for (int u = 0; u < 8; ++u) { float v = its[sq * 8 + u][k]; p2[u] += v * w2; p3[u] += v * w3; pS[u] += v * w4; }
  }
  for (int k = 0; k < 128; ++k) {
    float w2 = W2[(256 + k) * DK + j], w3 = W3[(256 + k) * DK + j];
#pragma unroll
    for (int u = 0; u < 8; ++u) { float v = als[sq * 8 + u + 1][k]; p2[u] += v * w2; p3[u] += v * w3; }
  }
  for (int k = 0; k < 128; ++k) {
    float w5 = W5[k * DK + j];
#pragma unroll
    for (int u = 0; u < 8; ++u) pY[u] += ens[sq * 8 + u][k] * w5;
  }
#pragma unroll
  for (int u = 0; u < 8; ++u) {
    int s = s0 + sq * 8 + u;
    if (s < 127) {
      int o = (b * 127 + s) * DK + j;
      ws[OFF_P2 + o] = p2[u]; ws[OFF_P3 + o] = p3[u];
      ws[OFF_PS + o] = pS[u]; ws[OFF_PY + o] = pY[u];
    }
  }
}

// ---------------- main recurrent kernel: 4 CUs per batch row, exchange hidden under MFMA ----------------
// grid 128 = slice(0..3) x b(0..31); block owns c in [64*slice, 64*slice+64), 512 thr.
// Per step (4 barriers): P1 [wave0: publish partial+flag; all: MFMA; waves>=2: prefetch issue;
// wave0: spin+gather->htld] bA | [HT store + A-dot/LG] bB | [B-dot] bC |
// [prefetch commit + X gamma/update/paired-pack + htp] bD.
// Cross-CU: agent-scope stores, wave-local vmcnt(0) drain before flag, monotone seq flags
// (zeroed each launch), parity double-buffer. Flag v => partner stored partial(v-1) and
// finished gather(v-2) -> overwrite-safe (writer at P1(s+2) spun for >= s+2 at P1(s+1)).
__global__ __launch_bounds__(512, 2) void kmain(
    const int* __restrict__ e_data, const float* __restrict__ qmat,
    const float* __restrict__ W2, const float* __restrict__ W3,
    const float* __restrict__ W4, const float* __restrict__ h0,
    float* ws)
{
  __shared__ char     hsb[16384];        // h slice bf16 [64 c][128 k] XOR-swizzled
  __shared__ uint32_t W4Lp[64][128];     // W4[128:256] bf16 pairs                (32KB)
  __shared__ u32x4    W4B[4][8][64];     // W4[0:128] MFMA B-frags                (32KB)
  __shared__ float    qbuf[3][64];       // q rows (own slice), 3-slot ring
  __shared__ float    PST[2][3][128];    // preacts r2,r3,rS, parity ring
  __shared__ float    LGs[128];
  __shared__ float    htld[128];
  __shared__ float    sbcp[4][128];
  __shared__ float    htp[2][128];

  const int bx = blockIdx.x;
  const int b = bx & 31, slice = bx >> 5;
  const int tid = threadIdx.x;
  const int lane = tid & 63, wv = tid >> 6;
  const int ct = wv >> 2, jt = wv & 3;
  const int lo = lane & 31, hi = lane >> 5;
  const int j = tid & 127;
  const int jA = tid >> 2, am = (tid >> 1) & 1, akh = tid & 1;
  const int kq = tid >> 7;
  const int jloc = jt * 32 + lo;

  float* cm = ws + OFF_CM + b * (2 * NSL * 128);     // [parity][slice][128]
  uint32_t* fg = (uint32_t*)(ws + OFF_FG) + b * NSL; // [slice]

  // ---- persistent registers: Aw (32) + hm (16) ----
  uint32_t Aw[32];
  {
    const float* Wm = am ? W3 : W2;
#pragma unroll
    for (int i = 0; i < 32; ++i) {
      float w0 = Wm[(384 + akh * 64 + 2 * i) * DK + jA];
      float w1 = Wm[(384 + akh * 64 + 2 * i + 1) * DK + jA];
      Aw[i] = pkbf(w0, w1);
    }
  }
  float hm[16];
#pragma unroll
  for (int r = 0; r < 16; ++r) {
    int cl = ct * 32 + (r & 3) + 8 * (r >> 2) + 4 * hi;
    hm[r] = h0[(slice * 64 + cl) * DK + jloc];
  }

  // ---- prologue LDS fills ----
#pragma unroll
  for (int it = 0; it < 16; ++it) {
    int idx = tid + it * 512, kp = idx >> 7, jj = idx & 127;
    W4Lp[kp][jj] = pkbf(W4[(128 + 2 * kp) * DK + jj], W4[(128 + 2 * kp + 1) * DK + jj]);
  }
  {
    uint32_t* w4b = (uint32_t*)&W4B[0][0][0];
#pragma unroll
    for (int it = 0; it < 16; ++it) {
      int idx = tid + it * 512;
      int w = idx & 3, l = (idx >> 2) & 63, kk = (idx >> 8) & 7, jb = idx >> 11;
      int llo = l & 31, lhi = l >> 5;
      int row = kk * 16 + lhi * 8 + 2 * w, col = jb * 32 + llo;
      w4b[idx] = pkbf(W4[row * DK + col], W4[(row + 1) * DK + col]);
    }
  }
  if (tid < 64) {
    qbuf[0][tid] = qmat[e_data[b * S + 0] * NC + slice * 64 + tid];
    qbuf[1][tid] = qmat[e_data[b * S + 1] * NC + slice * 64 + tid];
  }
  if (tid < 384) {
    int mm = tid >> 7, jj = tid & 127;
    int off = (mm == 0) ? OFF_P2 : (mm == 1) ? OFF_P3 : OFF_PS;
    PST[0][mm][jj] = ws[off + (b * 127 + 0) * DK + jj];
  }
#pragma unroll
  for (int r = 0; r < 16; ++r) {                 // pack h0 slice into hsb
    int cl = ct * 32 + (r & 3) + 8 * (r >> 2) + 4 * hi;
    *(uint16_t*)(hsb + cl * 256 + ((jloc * 2) ^ ((cl & 15) << 4))) = (uint16_t)pkbf(hm[r], 0.f);
  }
  if (tid < 128) htld[tid] = 0.f;
  __syncthreads();

  // ---- prologue: partial(0) = q(0) . h0 slice, exchange (flag 1), htld(0) ----
  {
    float ht = 0.f;
#pragma unroll
    for (int r = 0; r < 16; ++r) {
      int cl = ct * 32 + (r & 3) + 8 * (r >> 2) + 4 * hi;
      ht += qbuf[0][cl] * hm[r];
    }
    ht += __shfl_xor(ht, 32);
    if (hi == 0) htp[ct][jloc] = ht;
  }
  __syncthreads();
  if (tid < 128) {
    float p = htp[0][tid] + htp[1][tid];
    __hip_atomic_store(&cm[0 * (NSL * 128) + slice * 128 + tid], p,
                       __ATOMIC_RELAXED, __HIP_MEMORY_SCOPE_AGENT);
  }
  __syncthreads();                                   // drains partial stores
  if (tid == 0)
    __hip_atomic_store(&fg[slice], 1u, __ATOMIC_RELAXED, __HIP_MEMORY_SCOPE_AGENT);
  if (wv == 0) {
    for (;;) {
      uint32_t f = __hip_atomic_load(&fg[lane & 3], __ATOMIC_RELAXED, __HIP_MEMORY_SCOPE_AGENT);
      if (__all(f >= 1u)) break;
      __builtin_amdgcn_s_sleep(2);
    }
  }
  __syncthreads();
  {
    int sl = tid >> 7, jj = tid & 127;
    float v = __hip_atomic_load(&cm[0 * (NSL * 128) + sl * 128 + jj],
                                __ATOMIC_RELAXED, __HIP_MEMORY_SCOPE_AGENT);
    atomicAdd(&htld[jj], v);
  }
  __syncthreads();

#pragma unroll 1
  for (int s = 0; s < S - 1; ++s) {
    const int par = s & 1, parn = (s + 1) & 1;

    // ===== P1: wave0 publish partial(s); all MFMA; waves>=2 prefetch; wave0 spin+gather =====
    if (wv == 0 && s > 0) {
      float p0 = htp[0][lane] + htp[1][lane];
      float p1 = htp[0][64 + lane] + htp[1][64 + lane];
      __hip_atomic_store(&cm[par * (NSL * 128) + slice * 128 + lane], p0,
                         __ATOMIC_RELAXED, __HIP_MEMORY_SCOPE_AGENT);
      __hip_atomic_store(&cm[par * (NSL * 128) + slice * 128 + 64 + lane], p1,
                         __ATOMIC_RELAXED, __HIP_MEMORY_SCOPE_AGENT);
      asm volatile("s_waitcnt vmcnt(0)" ::: "memory");
      if (lane == 0)
        __hip_atomic_store(&fg[slice], (uint32_t)(s + 1), __ATOMIC_RELAXED, __HIP_MEMORY_SCOPE_AGENT);
    }
    float qld = 0.f, pld = 0.f;
    if (tid >= 448)
      qld = qmat[e_data[b * S + min(s + 2, S - 1)] * NC + slice * 64 + (tid - 448)];
    if (tid >= 128) {
      int mm = (tid - 128) >> 7, jj = tid & 127;
      int off = (mm == 0) ? OFF_P2 : (mm == 1) ? OFF_P3 : OFF_PS;
      pld = ws[off + (b * 127 + min(s + 1, 126)) * DK + jj];
    }

    f32x16 acc;
#pragma unroll
    for (int r = 0; r < 16; ++r) acc[r] = 0.f;
#pragma unroll
    for (int kk = 0; kk < 8; ++kk) {
      u32x4 bfr = W4B[jt][kk][lane];
      int cl = ct * 32 + lo;
      bf16x8 af = __builtin_bit_cast(bf16x8,
          *(const u32x4*)(hsb + cl * 256 + ((kk * 32 + hi * 16) ^ ((cl & 15) << 4))));
      acc = __builtin_amdgcn_mfma_f32_32x32x16_bf16(af, __builtin_bit_cast(bf16x8, bfr), acc, 0, 0, 0);
    }

    if (wv == 0 && s > 0) {
      uint32_t tgt = (uint32_t)(s + 1);
      for (;;) {
        uint32_t f = __hip_atomic_load(&fg[lane & 3], __ATOMIC_RELAXED, __HIP_MEMORY_SCOPE_AGENT);
        if (__all(f >= tgt)) break;
        __builtin_amdgcn_s_sleep(1);
      }
      asm volatile("" ::: "memory");
      float v0 = 0.f, v1 = 0.f;
#pragma unroll
      for (int sl = 0; sl < NSL; ++sl) {
        v0 += __hip_atomic_load(&cm[par * (NSL * 128) + sl * 128 + lane],
                                __ATOMIC_RELAXED, __HIP_MEMORY_SCOPE_AGENT);
        v1 += __hip_atomic_load(&cm[par * (NSL * 128) + sl * 128 + 64 + lane],
                                __ATOMIC_RELAXED, __HIP_MEMORY_SCOPE_AGENT);
      }
      htld[lane] = v0;
      htld[64 + lane] = v1;
    }
    __syncthreads(); // bA

    // ===== A-dot + LG (+ HT history store, slice 0) =====
    if (slice == 0 && s > 0 && tid < 128)
      ws[OFF_HT + (b * 127 + (s - 1)) * DK + tid] = htld[tid];
    {
      float p = 0.f;
#pragma unroll
      for (int t = 0; t < 16; ++t) {
        float4 h4 = *(const float4*)&htld[akh * 64 + 4 * t];
        uint32_t w0 = Aw[2 * t], w1 = Aw[2 * t + 1];
        p += bflo(w0) * h4.x + bfhi(w0) * h4.y + bflo(w1) * h4.z + bfhi(w1) * h4.w;
      }
      p += __shfl_xor(p, 1);
      float po = __shfl_xor(p, 2);
      float v2 = am ? po : p;
      float v3 = am ? p : po;
      v2 += PST[par][0][jA];
      v3 += PST[par][1][jA];
      float lg = sigm(v3) * sigm(2.f * v2);
      if ((tid & 3) == 0) LGs[jA] = lg;
    }
    __syncthreads(); // bB

    // ===== B-dot partials =====
    {
      float pB = 0.f;
#pragma unroll
      for (int t = 0; t < 8; ++t) {
        float4 g4 = *(const float4*)&LGs[kq * 32 + 4 * t];
        uint32_t w0 = W4Lp[kq * 16 + 2 * t][j], w1 = W4Lp[kq * 16 + 2 * t + 1][j];
        pB += bflo(w0) * g4.x + bfhi(w0) * g4.y + bflo(w1) * g4.z + bfhi(w1) * g4.w;
      }
      sbcp[kq][j] = pB;
    }
    __syncthreads(); // bC

    // ===== X: prefetch commit + gamma / h-update / paired pack + partial h_tilde =====
    if (tid >= 448) qbuf[(s + 2) % 3][tid - 448] = qld;
    if (tid >= 128) {
      int mm = (tid - 128) >> 7, jj = tid & 127;
      PST[parn][mm][jj] = pld;
    }
    {
      const float* qc = &qbuf[s % 3][0];
      const float* qn = &qbuf[(s + 1) % 3][0];
      float sb = PST[par][2][jloc] + sbcp[0][jloc] + sbcp[1][jloc] + sbcp[2][jloc] + sbcp[3][jloc];
      float sn = sb * NLOG2E;
      float lgj = LGs[jloc];
      float ht = 0.f;
      uint32_t vals[16];
#pragma unroll
      for (int q4 = 0; q4 < 4; ++q4) {
        int cbase = ct * 32 + 8 * q4 + 4 * hi;
        float4 qe4 = *(const float4*)&qc[cbase];
        float4 qn4 = *(const float4*)&qn[cbase];
#pragma unroll
        for (int rr = 0; rr < 4; ++rr) {
          int r = 4 * q4 + rr;
          float qe = (rr == 0) ? qe4.x : (rr == 1) ? qe4.y : (rr == 2) ? qe4.z : qe4.w;
          float qq = (rr == 0) ? qn4.x : (rr == 1) ? qn4.y : (rr == 2) ? qn4.z : qn4.w;
          float g = v_rcp(1.0f + v_exp2(fmaf(acc[r], NLOG2E, sn)));
          float hn = fmaf(g, hm[r], qe * lgj);
          hm[r] = hn; ht = fmaf(qq, hn, ht);
          float nb = __shfl_xor(hn, 1);
          vals[r] = pkbf(hn, nb);          // meaningful on even lanes (jloc even)
        }
      }
      if (!(lane & 1)) {
#pragma unroll
        for (int r = 0; r < 16; ++r) {
          int cl = ct * 32 + (r & 3) + 8 * (r >> 2) + 4 * hi;
          *(uint32_t*)(hsb + cl * 256 + ((jloc * 2) ^ ((cl & 15) << 4))) = vals[r];
        }
      }
      ht += __shfl_xor(ht, 32);
      if (hi == 0) htp[ct][jloc] = ht;
    }
    __syncthreads(); // bD
  }

  // ---- epilogue: exchange partial(127) (parity 1, flag 128) -> h_tilde(127) -> HT row 126
  if (wv == 0) {
    float p0 = htp[0][lane] + htp[1][lane];
    float p1 = htp[0][64 + lane] + htp[1][64 + lane];
    __hip_atomic_store(&cm[1 * (NSL * 128) + slice * 128 + lane], p0,
                       __ATOMIC_RELAXED, __HIP_MEMORY_SCOPE_AGENT);
    __hip_atomic_store(&cm[1 * (NSL * 128) + slice * 128 + 64 + lane], p1,
                       __ATOMIC_RELAXED, __HIP_MEMORY_SCOPE_AGENT);
    asm volatile("s_waitcnt vmcnt(0)" ::: "memory");
    if (lane == 0)
      __hip_atomic_store(&fg[slice], 128u, __ATOMIC_RELAXED, __HIP_MEMORY_SCOPE_AGENT);
    for (;;) {
      uint32_t f = __hip_atomic_load(&fg[lane & 3], __ATOMIC_RELAXED, __HIP_MEMORY_SCOPE_AGENT);
      if (__all(f >= 128u)) break;
      __builtin_amdgcn_s_sleep(1);
    }
    asm volatile("" ::: "memory");
    float v0 = 0.f, v1 = 0.f;
#pragma unroll
    for (int sl = 0; sl < NSL; ++sl) {
      v0 += __hip_atomic_load(&cm[1 * (NSL * 128) + sl * 128 + lane],
                              __ATOMIC_RELAXED, __HIP_MEMORY_SCOPE_AGENT);
      v1 += __hip_atomic_load(&cm[1 * (NSL * 128) + sl * 128 + 64 + lane],
                              __ATOMIC_RELAXED, __HIP_MEMORY_SCOPE_AGENT);
    }
    htld[lane] = v0;
    htld[64 + lane] = v1;
  }
  __syncthreads();
  if (slice == 0 && tid < 128)
    ws[OFF_HT + (b * 127 + 126) * DK + tid] = htld[tid];
}

// ---------------- kernel 2: deferred y = mean_j sigmoid(preY + h_tilde @ W5h) ----------------
__global__ __launch_bounds__(128) void k2_y(const float* __restrict__ ws, float* __restrict__ out)
{
  __shared__ float hts[8][128];
  __shared__ float part[2][8];
  int b = blockIdx.x >> 4, ch = blockIdx.x & 15, s0 = ch * 8;
  int j = threadIdx.x;
#pragma unroll
  for (int u = 0; u < 8; ++u) {
    int s = s0 + u;
    hts[u][j] = (s < 127) ? ws[OFF_HT + (b * 127 + s) * DK + j] : 0.f;
  }
  __syncthreads();
  float acc[8];
#pragma unroll
  for (int u = 0; u < 8; ++u) {
    int s = s0 + u;
    acc[u] = (s < 127) ? ws[OFF_PY + (b * 127 + s) * DK + j] : 0.f;
  }
  const float4* w5 = (const float4*)(ws + OFF_WT5 + j * DK);
#pragma unroll 8
  for (int i = 0; i < 32; ++i) {
    float4 w = w5[i];
#pragma unroll
    for (int u = 0; u < 8; ++u) {
      float4 h4 = *(const float4*)&hts[u][4 * i];
      acc[u] += w.x * h4.x + w.y * h4.y + w.z * h4.z + w.w * h4.w;
    }
  }
#pragma unroll
  for (int u = 0; u < 8; ++u) {
    float v = sigm(acc[u]);
#pragma unroll
    for (int off = 32; off >= 1; off >>= 1) v += __shfl_xor(v, off);
    if ((j & 63) == 0) part[j >> 6][u] = v;
  }
  __syncthreads();
  if (j < 8) {
    int s = s0 + j;
    if (s < 127) out[b * S + s + 1] = (part[0][j] + part[1][j]) * (1.0f / 128.0f);
  }
  if (j == 0 && ch == 0) out[b * S] = 0.f;
}

extern "C" void kernel_launch(void* const* d_in, const int* in_sizes, int n_in,
                              void* d_out, int out_size, void* d_ws, size_t ws_size,
                              hipStream_t stream)
{
  (void)in_sizes; (void)n_in; (void)out_size; (void)ws_size;
  const int*   e_data  = (const int*)  d_in[0];
  const int*   at_data = (const int*)  d_in[1];
  const int*   it_data = (const int*)  d_in[2];
  const float* a_data  = (const float*)d_in[3];
  const float* qmat    = (const float*)d_in[4];
  const float* e_E     = (const float*)d_in[5];
  const float* at_E    = (const float*)d_in[6];
  const float* it_E    = (const float*)d_in[7];
  const float* W1 = (const float*)d_in[8];  const float* b1 = (const float*)d_in[9];
  const float* W2 = (const float*)d_in[10]; const float* b2 = (const float*)d_in[11];
  const float* W3 = (const float*)d_in[12]; const float* b3 = (const float*)d_in[13];
  const float* W4 = (const float*)d_in[14]; const float* b4 = (const float*)d_in[15];
  const float* W5 = (const float*)d_in[16]; const float* b5 = (const float*)d_in[17];
  const float* h0 = (const float*)d_in[18];
  float* ws  = (float*)d_ws;
  float* out = (float*)d_out;

  // zero the cross-CU seq flags (graph-capture-safe, replay-safe)
  hipMemsetAsync((char*)d_ws + (size_t)OFF_FG * 4, 0, NB * NSL * 4, stream);

  k0_al <<<128, 512, 0, stream>>>(e_data, at_data, a_data, e_E, at_E, W1, b1, ws);
  kT_tr <<<64, 256, 0, stream>>>(W5, ws);
  k1_pre<<<128, 512, 0, stream>>>(e_data, it_data, it_E, e_E, W2, b2, W3, b3, W4, b4, W5, b5, ws);
  kmain <<<128, 512, 0, stream>>>(e_data, qmat, W2, W3, W4, h0, ws);
  k2_y  <<<512, 128, 0, stream>>>(ws, out);
}

// Round 9
// 494.289 us; speedup vs baseline: 5.2278x; 1.1708x over previous
//
#include <hip/hip_runtime.h>
#include <stdint.h>

#define S   128
#define NB  32
#define NC  256
#define DK  128
#define NSL 4

typedef __bf16 bf16x8 __attribute__((ext_vector_type(8)));
typedef float  f32x16 __attribute__((ext_vector_type(16)));
typedef unsigned int u32x4 __attribute__((ext_vector_type(4)));
typedef unsigned int u32x2 __attribute__((ext_vector_type(2)));
static_assert(sizeof(bf16x8) == 16, "bf16x8 size");
static_assert(sizeof(u32x4) == 16, "u32x4 size");

// d_ws layout (float offsets).
#define OFF_AL   0            // [32][128][128] AL; later OFF_HT (reduced h_tilde) reuse
#define OFF_HT   OFF_AL
#define OFF_P2   524288
#define OFF_P3   1044480
#define OFF_PS   1564672
#define OFF_PY   2084864
#define OFF_WT5  2654208
#define OFF_CM   2670592      // u64 comm [32 b][2 parity][4 slice][128 j] = 256KB (memset 0 each launch)

__device__ __forceinline__ float v_exp2(float x){ float r; asm("v_exp_f32 %0, %1" : "=v"(r) : "v"(x)); return r; }
__device__ __forceinline__ float v_rcp (float x){ float r; asm("v_rcp_f32 %0, %1" : "=v"(r) : "v"(x)); return r; }
__device__ __forceinline__ float sigm(float x){ return v_rcp(1.0f + v_exp2(x * -1.4426950408889634f)); }
__device__ __forceinline__ uint32_t pkbf(float lo, float hi){
  uint32_t r; asm("v_cvt_pk_bf16_f32 %0, %1, %2" : "=v"(r) : "v"(lo), "v"(hi)); return r;
}
__device__ __forceinline__ float bflo(uint32_t w){ return __builtin_bit_cast(float, w << 16); }
__device__ __forceinline__ float bfhi(uint32_t w){ return __builtin_bit_cast(float, w & 0xffff0000u); }
#define NLOG2E (-1.4426950408889634f)

// ---------------- kernel 0: AL = concat(e_emb, at_emb, a*ones50) @ W1 + b1 ----------------
__global__ __launch_bounds__(512) void k0_al(
    const int* __restrict__ e_data, const int* __restrict__ at_data,
    const float* __restrict__ a_data, const float* __restrict__ e_E,
    const float* __restrict__ at_E, const float* __restrict__ W1,
    const float* __restrict__ b1, float* __restrict__ ws)
{
  __shared__ float ein[32][128];
  __shared__ float atin[32][128];
  int b = blockIdx.x >> 2, q4 = blockIdx.x & 3, t0 = q4 * 32;
  for (int idx = threadIdx.x; idx < 32 * 128; idx += 512) {
    int r = idx >> 7, j = idx & 127;
    int ev  = e_data [b * S + t0 + r];
    int atv = at_data[b * S + t0 + r];
    ein [r][j] = e_E [ev  * DK + j];
    atin[r][j] = at_E[atv * DK + j];
  }
  __syncthreads();
  int j = threadIdx.x & 127, tq = threadIdx.x >> 7;
  float w1s = 0.f;
  for (int d = 0; d < 50; ++d) w1s += W1[(256 + d) * DK + j];
  float acc[8];
#pragma unroll
  for (int u = 0; u < 8; ++u) {
    int t = t0 + tq * 8 + u;
    acc[u] = b1[j] + a_data[b * S + t] * w1s;
  }
  for (int k = 0; k < 128; ++k) {
    float w = W1[k * DK + j];
#pragma unroll
    for (int u = 0; u < 8; ++u) acc[u] += ein[tq * 8 + u][k] * w;
  }
  for (int k = 0; k < 128; ++k) {
    float w = W1[(128 + k) * DK + j];
#pragma unroll
    for (int u = 0; u < 8; ++u) acc[u] += atin[tq * 8 + u][k] * w;
  }
#pragma unroll
  for (int u = 0; u < 8; ++u)
    ws[OFF_AL + (b * S + t0 + tq * 8 + u) * DK + j] = acc[u];
}

// ---------------- kernel T: transpose W5 h-block into ws ----------------
__global__ __launch_bounds__(256) void kT_tr(const float* __restrict__ W5, float* __restrict__ ws)
{
  int idx = blockIdx.x * 256 + threadIdx.x;
  int j = idx >> 7, k = idx & 127;
  ws[OFF_WT5 + j * DK + k] = W5[(128 + k) * DK + j];
}

// ---------------- kernel 1: carry-independent per-step preactivations ----------------
__global__ __launch_bounds__(512) void k1_pre(
    const int* __restrict__ e_data, const int* __restrict__ it_data,
    const float* __restrict__ it_E, const float* __restrict__ e_E,
    const float* __restrict__ W2, const float* __restrict__ b2,
    const float* __restrict__ W3, const float* __restrict__ b3,
    const float* __restrict__ W4, const float* __restrict__ b4,
    const float* __restrict__ W5, const float* __restrict__ b5,
    float* __restrict__ ws)
{
  __shared__ float als[33][128];
  __shared__ float its[32][128];
  __shared__ float ens[32][128];
  int b = blockIdx.x >> 2, sh = blockIdx.x & 3, s0 = sh * 32;
  for (int idx = threadIdx.x; idx < 33 * 128; idx += 512) {
    int r = idx >> 7, j = idx & 127;
    int srow = s0 - 1 + r;
    als[r][j] = (srow >= 0) ? ws[OFF_AL + (b * S + srow) * DK + j] : 0.f;
  }
  for (int idx = threadIdx.x; idx < 32 * 128; idx += 512) {
    int r = idx >> 7, j = idx & 127;
    int itv = it_data[b * S + s0 + r];
    its[r][j] = it_E[itv * DK + j];
    int sg = s0 + r + 1; if (sg > 127) sg = 127;
    int ev = e_data[b * S + sg];
    ens[r][j] = e_E[ev * DK + j];
  }
  __syncthreads();
  int j = threadIdx.x & 127, sq = threadIdx.x >> 7;
  float p2[8], p3[8], pS[8], pY[8];
#pragma unroll
  for (int u = 0; u < 8; ++u) { p2[u] = b2[j]; p3[u] = b3[j]; pS[u] = b4[j]; pY[u] = b5[j]; }
  for (int k = 0; k < 128; ++k) {
    float w2 = W2[k * DK + j], w3 = W3[k * DK + j];
#pragma unroll
    for (int u = 0; u < 8; ++u) { float v = als[sq * 8 + u][k]; p2[u] += v * w2; p3[u] += v * w3; }
  }
  for (int k = 0; k < 128; ++k) {
    float w2 = W2[(128 + k) * DK + j], w3 = W3[(128 + k) * DK + j], w4 = W4[(256 + k) * DK + j];
#pragma unroll
    for (int u = 0; u < 8; ++u) { float v = its[sq * 8 + u][k]; p2[u] += v * w2; p3[u] += v * w3; pS[u] += v * w4; }
  }
  for (int k = 0; k < 128; ++k) {
    float w2 = W2[(256 + k) * DK + j], w3 = W3[(256 + k) * DK + j];
#pragma unroll
    for (int u = 0; u < 8; ++u) { float v = als[sq * 8 + u + 1][k]; p2[u] += v * w2; p3[u] += v * w3; }
  }
  for (int k = 0; k < 128; ++k) {
    float w5 = W5[k * DK + j];
#pragma unroll
    for (int u = 0; u < 8; ++u) pY[u] += ens[sq * 8 + u][k] * w5;
  }
#pragma unroll
  for (int u = 0; u < 8; ++u) {
    int s = s0 + sq * 8 + u;
    if (s < 127) {
      int o = (b * 127 + s) * DK + j;
      ws[OFF_P2 + o] = p2[u]; ws[OFF_P3 + o] = p3[u];
      ws[OFF_PS + o] = pS[u]; ws[OFF_PY + o] = pY[u];
    }
  }
}

// ---------------- main recurrent kernel: 4 CUs/row, tag-in-data exchange, 3 barriers ----------------
// grid 128 = slice(0..3) x b(0..31); block owns c in [64*slice,+64), 512 thr, wave (ct,jt).
// Registers: Aw 32 (A-dot weights), W4Br 32 (MFMA B-frags), W4Lr 32 (B-dot weights), hm 16.
// hsb: h bf16 [64c][128k], byte = cl*256 + ((j*2) ^ ((cl&15)<<3)) -> 2-way max on b64 reads.
// Exchange: partial[j] published as atomic u64 (f32bits<<32 | tag=s+1), parity slot; gather =
// 8 u64 loads/lane + tag check + retry. One IC round-trip, no flags, no vmcnt drains.
// Step: P1 [wave0 publish; all MFMA (A b64-pairs from hsb, B regs); waves1-7 prefetch issue;
// wave0 gather->htld] bA | P2 [HT store + A-dot butterfly -> LGs] bB |
// X [prefetch commit + inline B-dot (hi-split + shfl32) + gamma/update/pack + htp] bD.
__global__ __launch_bounds__(512, 2) void kmain(
    const int* __restrict__ e_data, const float* __restrict__ qmat,
    const float* __restrict__ W2, const float* __restrict__ W3,
    const float* __restrict__ W4, const float* __restrict__ h0,
    float* ws)
{
  __shared__ char  hsb[16384];
  __shared__ float qbuf[3][64];
  __shared__ float PST[2][3][128];
  __shared__ float LGs[128];
  __shared__ float htld[128];
  __shared__ float htp[2][128];

  const int bx = blockIdx.x;
  const int b = bx & 31, slice = bx >> 5;
  const int tid = threadIdx.x;
  const int lane = tid & 63, wv = tid >> 6;
  const int ct = wv >> 2, jt = wv & 3;
  const int lo = lane & 31, hi = lane >> 5;
  const int jA = tid >> 2, am = (tid >> 1) & 1, akh = tid & 1;
  const int jloc = jt * 32 + lo;

  unsigned long long* cm64 = (unsigned long long*)(ws + OFF_CM) + (size_t)b * (2 * NSL * 128);

  // ---- persistent registers ----
  uint32_t Aw[32];
  {
    const float* Wm = am ? W3 : W2;
#pragma unroll
    for (int i = 0; i < 32; ++i) {
      float w0 = Wm[(384 + akh * 64 + 2 * i) * DK + jA];
      float w1 = Wm[(384 + akh * 64 + 2 * i + 1) * DK + jA];
      Aw[i] = pkbf(w0, w1);
    }
  }
  u32x4 W4Br[8];                               // MFMA B-frags: B[k][col=jloc], k-span per (kk,hi)
#pragma unroll
  for (int kk = 0; kk < 8; ++kk) {
    float w[8];
#pragma unroll
    for (int e = 0; e < 8; ++e) w[e] = W4[(kk * 16 + hi * 8 + e) * DK + jloc];
    u32x4 d;
    d[0] = pkbf(w[0], w[1]); d[1] = pkbf(w[2], w[3]);
    d[2] = pkbf(w[4], w[5]); d[3] = pkbf(w[6], w[7]);
    W4Br[kk] = d;
  }
  uint32_t W4Lr[32];                           // B-dot weights: W4[128 + hi*64 + k][jloc]
#pragma unroll
  for (int t = 0; t < 32; ++t)
    W4Lr[t] = pkbf(W4[(128 + hi * 64 + 2 * t) * DK + jloc],
                   W4[(128 + hi * 64 + 2 * t + 1) * DK + jloc]);
  float hm[16];
#pragma unroll
  for (int r = 0; r < 16; ++r) {
    int cl = ct * 32 + (r & 3) + 8 * (r >> 2) + 4 * hi;
    hm[r] = h0[(slice * 64 + cl) * DK + jloc];
  }

  // ---- prologue LDS fills ----
  if (tid < 64) {
    qbuf[0][tid] = qmat[e_data[b * S + 0] * NC + slice * 64 + tid];
    qbuf[1][tid] = qmat[e_data[b * S + 1] * NC + slice * 64 + tid];
  }
  if (tid < 384) {
    int mm = tid >> 7, jj = tid & 127;
    int off = (mm == 0) ? OFF_P2 : (mm == 1) ? OFF_P3 : OFF_PS;
    PST[0][mm][jj] = ws[off + (b * 127 + 0) * DK + jj];
  }
#pragma unroll
  for (int r = 0; r < 16; ++r) {               // pack h0 slice into hsb (8B-granule swizzle)
    int cl = ct * 32 + (r & 3) + 8 * (r >> 2) + 4 * hi;
    *(uint16_t*)(hsb + cl * 256 + ((jloc * 2) ^ ((cl & 15) << 3))) = (uint16_t)pkbf(hm[r], 0.f);
  }
  __syncthreads();

  // ---- prologue: htp = per-slice partial of q(0).h0 ----
  {
    float ht = 0.f;
#pragma unroll
    for (int r = 0; r < 16; ++r) {
      int cl = ct * 32 + (r & 3) + 8 * (r >> 2) + 4 * hi;
      ht += qbuf[0][cl] * hm[r];
    }
    ht += __shfl_xor(ht, 32);
    if (hi == 0) htp[ct][jloc] = ht;
  }
  __syncthreads();

#pragma unroll 1
  for (int s = 0; s < S - 1; ++s) {
    const int par = s & 1;

    // ===== P1: wave0 publish partial(s) tag s+1; all MFMA; waves1-7 prefetch issue =====
    if (wv == 0) {
#pragma unroll
      for (int hf = 0; hf < 2; ++hf) {
        float p = htp[0][hf * 64 + lane] + htp[1][hf * 64 + lane];
        unsigned long long pk = ((unsigned long long)__builtin_bit_cast(uint32_t, p) << 32)
                              | (unsigned long long)(uint32_t)(s + 1);
        __hip_atomic_store(&cm64[par * (NSL * 128) + slice * 128 + hf * 64 + lane], pk,
                           __ATOMIC_RELAXED, __HIP_MEMORY_SCOPE_AGENT);
      }
    }
    float qld = 0.f, pld = 0.f;
    if (tid >= 448)
      qld = qmat[e_data[b * S + min(s + 2, S - 1)] * NC + slice * 64 + (tid - 448)];
    if (tid >= 128) {
      int mm = (tid - 128) >> 7, jj = tid & 127;
      int off = (mm == 0) ? OFF_P2 : (mm == 1) ? OFF_P3 : OFF_PS;
      pld = ws[off + (b * 127 + min(s + 1, 126)) * DK + jj];
    }

    // MFMA: pre[c,jloc] = h_bf16 @ W4h (A: 2x ds_read_b64 per kk; B: regs)
    f32x16 acc;
#pragma unroll
    for (int r = 0; r < 16; ++r) acc[r] = 0.f;
    {
      int cl = ct * 32 + lo, swz = (cl & 15) << 3;
      const char* base = hsb + cl * 256;
#pragma unroll
      for (int kk = 0; kk < 8; ++kk) {
        u32x2 a0 = *(const u32x2*)(base + ((kk * 32 + hi * 16) ^ swz));
        u32x2 a1 = *(const u32x2*)(base + ((kk * 32 + hi * 16 + 8) ^ swz));
        u32x4 af4; af4[0] = a0[0]; af4[1] = a0[1]; af4[2] = a1[0]; af4[3] = a1[1];
        acc = __builtin_amdgcn_mfma_f32_32x32x16_bf16(
            __builtin_bit_cast(bf16x8, af4), __builtin_bit_cast(bf16x8, W4Br[kk]), acc, 0, 0, 0);
      }
    }

    // wave0: gather 4 slices' tagged partials (retry until fresh), sum -> htld
    if (wv == 0) {
      unsigned long long g[4][2];
      const uint32_t tgt = (uint32_t)(s + 1);
      for (;;) {
        bool ok = true;
#pragma unroll
        for (int sl = 0; sl < NSL; ++sl)
#pragma unroll
          for (int hf = 0; hf < 2; ++hf) {
            g[sl][hf] = __hip_atomic_load(&cm64[par * (NSL * 128) + sl * 128 + hf * 64 + lane],
                                          __ATOMIC_RELAXED, __HIP_MEMORY_SCOPE_AGENT);
            ok &= ((uint32_t)g[sl][hf] == tgt);
          }
        if (__all(ok)) break;
        __builtin_amdgcn_s_sleep(1);
      }
      float v0 = 0.f, v1 = 0.f;
#pragma unroll
      for (int sl = 0; sl < NSL; ++sl) {
        v0 += __builtin_bit_cast(float, (uint32_t)(g[sl][0] >> 32));
        v1 += __builtin_bit_cast(float, (uint32_t)(g[sl][1] >> 32));
      }
      htld[lane] = v0;
      htld[64 + lane] = v1;
    }
    __syncthreads(); // bA

    // ===== P2: HT history store + A-dot butterfly -> LG =====
    if (slice == 0 && s > 0 && tid < 128)
      ws[OFF_HT + (b * 127 + (s - 1)) * DK + tid] = htld[tid];
    {
      float p = 0.f;
#pragma unroll
      for (int t = 0; t < 16; ++t) {
        float4 h4 = *(const float4*)&htld[akh * 64 + 4 * t];
        uint32_t w0 = Aw[2 * t], w1 = Aw[2 * t + 1];
        p += bflo(w0) * h4.x + bfhi(w0) * h4.y + bflo(w1) * h4.z + bfhi(w1) * h4.w;
      }
      p += __shfl_xor(p, 1);
      float po = __shfl_xor(p, 2);
      float v2 = am ? po : p;
      float v3 = am ? p : po;
      v2 += PST[par][0][jA];
      v3 += PST[par][1][jA];
      float lg = sigm(v3) * sigm(2.f * v2);
      if ((tid & 3) == 0) LGs[jA] = lg;
    }
    __syncthreads(); // bB

    // ===== X: prefetch commit + inline B-dot + gamma / h-update / pack + htp =====
    if (tid >= 448) qbuf[(s + 2) % 3][tid - 448] = qld;
    if (tid >= 128) {
      int mm = (tid - 128) >> 7, jj = tid & 127;
      PST[(s + 1) & 1][mm][jj] = pld;
    }
    {
      // B-dot: half-k per thread (hi), + shfl32 partner sum
      float pB = 0.f;
#pragma unroll
      for (int t2 = 0; t2 < 16; ++t2) {
        float4 g4 = *(const float4*)&LGs[hi * 64 + 4 * t2];
        uint32_t w0 = W4Lr[2 * t2], w1 = W4Lr[2 * t2 + 1];
        pB += bflo(w0) * g4.x + bfhi(w0) * g4.y + bflo(w1) * g4.z + bfhi(w1) * g4.w;
      }
      pB += __shfl_xor(pB, 32);
      float sb = PST[par][2][jloc] + pB;
      float sn = sb * NLOG2E;
      float lgj = LGs[jloc];
      const float* qc = &qbuf[s % 3][0];
      const float* qn = &qbuf[(s + 1) % 3][0];
      float ht = 0.f;
      uint32_t vals[16];
#pragma unroll
      for (int q4 = 0; q4 < 4; ++q4) {
        int cbase = ct * 32 + 8 * q4 + 4 * hi;
        float4 qe4 = *(const float4*)&qc[cbase];
        float4 qn4 = *(const float4*)&qn[cbase];
#pragma unroll
        for (int rr = 0; rr < 4; ++rr) {
          int r = 4 * q4 + rr;
          float qe = (rr == 0) ? qe4.x : (rr == 1) ? qe4.y : (rr == 2) ? qe4.z : qe4.w;
          float qq = (rr == 0) ? qn4.x : (rr == 1) ? qn4.y : (rr == 2) ? qn4.z : qn4.w;
          float g = v_rcp(1.0f + v_exp2(fmaf(acc[r], NLOG2E, sn)));
          float hn = fmaf(g, hm[r], qe * lgj);
          hm[r] = hn; ht = fmaf(qq, hn, ht);
          float nb = __shfl_xor(hn, 1);
          vals[r] = pkbf(hn, nb);              // even lanes hold (jloc, jloc+1) pair
        }
      }
      if (!(lane & 1)) {
#pragma unroll
        for (int r = 0; r < 16; ++r) {
          int cl = ct * 32 + (r & 3) + 8 * (r >> 2) + 4 * hi;
          *(uint32_t*)(hsb + cl * 256 + ((jloc * 2) ^ ((cl & 15) << 3))) = vals[r];
        }
      }
      ht += __shfl_xor(ht, 32);
      if (hi == 0) htp[ct][jloc] = ht;
    }
    __syncthreads(); // bD
  }

  // ---- tail: exchange partial(127) (tag 128, parity 1) -> htld -> HT row 126 ----
  if (wv == 0) {
#pragma unroll
    for (int hf = 0; hf < 2; ++hf) {
      float p = htp[0][hf * 64 + lane] + htp[1][hf * 64 + lane];
      unsigned long long pk = ((unsigned long long)__builtin_bit_cast(uint32_t, p) << 32)
                            | 128ull;
      __hip_atomic_store(&cm64[1 * (NSL * 128) + slice * 128 + hf * 64 + lane], pk,
                         __ATOMIC_RELAXED, __HIP_MEMORY_SCOPE_AGENT);
    }
    unsigned long long g[4][2];
    for (;;) {
      bool ok = true;
#pragma unroll
      for (int sl = 0; sl < NSL; ++sl)
#pragma unroll
        for (int hf = 0; hf < 2; ++hf) {
          g[sl][hf] = __hip_atomic_load(&cm64[1 * (NSL * 128) + sl * 128 + hf * 64 + lane],
                                        __ATOMIC_RELAXED, __HIP_MEMORY_SCOPE_AGENT);
          ok &= ((uint32_t)g[sl][hf] == 128u);
        }
      if (__all(ok)) break;
      __builtin_amdgcn_s_sleep(1);
    }
    float v0 = 0.f, v1 = 0.f;
#pragma unroll
    for (int sl = 0; sl < NSL; ++sl) {
      v0 += __builtin_bit_cast(float, (uint32_t)(g[sl][0] >> 32));
      v1 += __builtin_bit_cast(float, (uint32_t)(g[sl][1] >> 32));
    }
    htld[lane] = v0;
    htld[64 + lane] = v1;
  }
  __syncthreads();
  if (slice == 0 && tid < 128)
    ws[OFF_HT + (b * 127 + 126) * DK + tid] = htld[tid];
}

// ---------------- kernel 2: deferred y = mean_j sigmoid(preY + h_tilde @ W5h) ----------------
__global__ __launch_bounds__(128) void k2_y(const float* __restrict__ ws, float* __restrict__ out)
{
  __shared__ float hts[8][128];
  __shared__ float part[2][8];
  int b = blockIdx.x >> 4, ch = blockIdx.x & 15, s0 = ch * 8;
  int j = threadIdx.x;
#pragma unroll
  for (int u = 0; u < 8; ++u) {
    int s = s0 + u;
    hts[u][j] = (s < 127) ? ws[OFF_HT + (b * 127 + s) * DK + j] : 0.f;
  }
  __syncthreads();
  float acc[8];
#pragma unroll
  for (int u = 0; u < 8; ++u) {
    int s = s0 + u;
    acc[u] = (s < 127) ? ws[OFF_PY + (b * 127 + s) * DK + j] : 0.f;
  }
  const float4* w5 = (const float4*)(ws + OFF_WT5 + j * DK);
#pragma unroll 8
  for (int i = 0; i < 32; ++i) {
    float4 w = w5[i];
#pragma unroll
    for (int u = 0; u < 8; ++u) {
      float4 h4 = *(const float4*)&hts[u][4 * i];
      acc[u] += w.x * h4.x + w.y * h4.y + w.z * h4.z + w.w * h4.w;
    }
  }
#pragma unroll
  for (int u = 0; u < 8; ++u) {
    float v = sigm(acc[u]);
#pragma unroll
    for (int off = 32; off >= 1; off >>= 1) v += __shfl_xor(v, off);
    if ((j & 63) == 0) part[j >> 6][u] = v;
  }
  __syncthreads();
  if (j < 8) {
    int s = s0 + j;
    if (s < 127) out[b * S + s + 1] = (part[0][j] + part[1][j]) * (1.0f / 128.0f);
  }
  if (j == 0 && ch == 0) out[b * S] = 0.f;
}

extern "C" void kernel_launch(void* const* d_in, const int* in_sizes, int n_in,
                              void* d_out, int out_size, void* d_ws, size_t ws_size,
                              hipStream_t stream)
{
  (void)in_sizes; (void)n_in; (void)out_size; (void)ws_size;
  const int*   e_data  = (const int*)  d_in[0];
  const int*   at_data = (const int*)  d_in[1];
  const int*   it_data = (const int*)  d_in[2];
  const float* a_data  = (const float*)d_in[3];
  const float* qmat    = (const float*)d_in[4];
  const float* e_E     = (const float*)d_in[5];
  const float* at_E    = (const float*)d_in[6];
  const float* it_E    = (const float*)d_in[7];
  const float* W1 = (const float*)d_in[8];  const float* b1 = (const float*)d_in[9];
  const float* W2 = (const float*)d_in[10]; const float* b2 = (const float*)d_in[11];
  const float* W3 = (const float*)d_in[12]; const float* b3 = (const float*)d_in[13];
  const float* W4 = (const float*)d_in[14]; const float* b4 = (const float*)d_in[15];
  const float* W5 = (const float*)d_in[16]; const float* b5 = (const float*)d_in[17];
  const float* h0 = (const float*)d_in[18];
  float* ws  = (float*)d_ws;
  float* out = (float*)d_out;

  // zero the tagged-comm region (tags must start != any step tag)
  hipMemsetAsync((char*)d_ws + (size_t)OFF_CM * 4, 0, (size_t)NB * 2 * NSL * 128 * 8, stream);

  k0_al <<<128, 512, 0, stream>>>(e_data, at_data, a_data, e_E, at_E, W1, b1, ws);
  kT_tr <<<64, 256, 0, stream>>>(W5, ws);
  k1_pre<<<128, 512, 0, stream>>>(e_data, it_data, it_E, e_E, W2, b2, W3, b3, W4, b4, W5, b5, ws);
  kmain <<<128, 512, 0, stream>>>(e_data, qmat, W2, W3, W4, h0, ws);
  k2_y  <<<512, 128, 0, stream>>>(ws, out);
}